// Round 4
// baseline (640.837 us; speedup 1.0000x reference)
//
#include <hip/hip_runtime.h>
#include <hip/hip_bf16.h>

#define Bb 2
#define HD 96
#define DI 192
#define LL 4096
#define Kd 4
#define Ns 16
#define Rr 6
#define SEG 128
#define SEGLEN 32
#define NBKCN (Bb*Kd*DI*Ns)   // 24576
#define LNEPS 1e-5f
#define RW 40                  // padded dblp row: 6 dt | 16 B | 16 C | 2 pad

// 1x1 conv, 8 outputs/thread
__global__ __launch_bounds__(256) void k_conv1x1(const float* __restrict__ x,
    const float* __restrict__ w, float* __restrict__ out, int Cin, int Cout) {
  int l = blockIdx.x*256 + threadIdx.x;
  int o0 = blockIdx.y*8;
  int b = blockIdx.z;
  const float* xb = x + ((size_t)b*Cin)*LL + l;
  const float* w0 = w + (size_t)o0*Cin;
  float acc[8];
  #pragma unroll
  for (int q=0;q<8;q++) acc[q]=0.f;
  for (int i=0;i<Cin;i++) {
    float xv = xb[(size_t)i*LL];
    #pragma unroll
    for (int q=0;q<8;q++) acc[q] += w0[(size_t)q*Cin + i]*xv;
  }
  float* ob = out + ((size_t)b*Cout + o0)*LL + l;
  #pragma unroll
  for (int q=0;q<8;q++) ob[(size_t)q*LL] = acc[q];
}

// channel LayerNorm in-place (LN1, 96 ch)
__global__ __launch_bounds__(256) void k_chanln(float* __restrict__ t,
    const float* __restrict__ g, const float* __restrict__ be, int C) {
  int tt = blockIdx.x*256 + threadIdx.x;
  int l = tt & (LL-1); int b = tt >> 12;
  float* col = t + (size_t)b*C*LL + l;
  float s=0.f, s2=0.f;
  for (int i=0;i<C;i++) { float v = col[(size_t)i*LL]; s+=v; s2+=v*v; }
  float mu = s/(float)C;
  float var = s2/(float)C - mu*mu;
  float r = rsqrtf(var + LNEPS);
  for (int i=0;i<C;i++) {
    float v = col[(size_t)i*LL];
    col[(size_t)i*LL] = (v-mu)*r*g[i] + be[i];
  }
}

// depthwise 3x3 + bias + silu, output CHANNEL-LAST v_t[b][p][c] via LDS transpose
// block = (h-row, b); 192 threads: phase1 (dg=t>>6, w=t&63), phase2 (c=t)
__global__ __launch_bounds__(192) void k_dwconv_silu_t(const float* __restrict__ hp,
    const float* __restrict__ wgt, const float* __restrict__ bias, float* __restrict__ v_t) {
  __shared__ float lds[DI*65];
  int t = threadIdx.x;
  int h = blockIdx.x, b = blockIdx.y;
  int w0 = t & 63, dg = t >> 6;
  for (int dd=0; dd<64; ++dd) {
    int d = dg*64 + dd;
    const float* src = hp + ((size_t)b*DI + d)*LL;
    const float* wk = wgt + d*9;
    float acc = bias[d];
    #pragma unroll
    for (int dy=-1; dy<=1; dy++) {
      int hh = h+dy;
      if (hh < 0 || hh >= 64) continue;
      #pragma unroll
      for (int dx=-1; dx<=1; dx++) {
        int ww = w0+dx;
        if (ww < 0 || ww >= 64) continue;
        acc += wk[(dy+1)*3 + (dx+1)] * src[hh*64 + ww];
      }
    }
    lds[d*65 + w0] = acc / (1.f + __expf(-acc));
  }
  __syncthreads();
  int c = t;
  for (int i=0;i<64;i++)
    v_t[((size_t)b*LL + h*64 + i)*DI + c] = lds[c*65 + i];
}

// dblp[b][k][p][40] = W_k(38x192) . v_t_row(p)   (p = ORIGINAL position)
// block = (ptile64, b), 256 threads (k=t>>6, p=t&63); LDS-staged v rows
__global__ __launch_bounds__(256) void k_proj(const float* __restrict__ v_t,
    const float* __restrict__ xpw, float* __restrict__ dblp) {
  __shared__ float lds[64*196];
  int t = threadIdx.x;
  int pt = blockIdx.x, b = blockIdx.y;
  const float* src = v_t + ((size_t)b*LL + pt*64)*DI;
  for (int idx=t; idx<64*DI; idx+=256) {
    int p = idx/DI, c = idx - p*DI;
    lds[p*196 + c] = src[idx];
  }
  __syncthreads();
  int k = t>>6, p = t&63;
  float acc[38];
  #pragma unroll
  for (int d=0;d<38;d++) acc[d]=0.f;
  const float4* W4 = (const float4*)(xpw + (size_t)k*38*DI);
  const float4* row4 = (const float4*)(lds + p*196);
  for (int c4=0;c4<48;c4++) {
    float4 xv = row4[c4];
    #pragma unroll
    for (int d=0;d<38;d++) {
      float4 wv = W4[(size_t)d*48 + c4];
      acc[d] += xv.x*wv.x + xv.y*wv.y + xv.z*wv.z + xv.w*wv.w;
    }
  }
  float* o = dblp + (((size_t)b*4 + k)*LL + pt*64 + p)*RW;
  #pragma unroll
  for (int d=0;d<38;d++) o[d] = acc[d];
}

// ---- scan pass A: zero-init per-seg end state + sum(dt) ----
// block = (s, pair, b); pair0 = dirs(0,2), pair1 = dirs(1,3); 192 threads (c)
__global__ __launch_bounds__(192) void k_scanA(const float* __restrict__ v_t,
    const float* __restrict__ dblp, const float* __restrict__ dtw,
    const float* __restrict__ dtb, const float* __restrict__ A_log,
    float* __restrict__ hend, float* __restrict__ sdt_o) {
  int c = threadIdx.x;
  int s = blockIdx.x, pair = blockIdx.y, b = blockIdx.z;
  int kA = pair ? 1 : 0, kB = pair ? 3 : 2;
  int segA = s, segB = SEG-1-s;
  int pbase = pair ? ((s&1)*2048 + (s>>1)) : s*32;
  int pstr  = pair ? 64 : 1;
  float wA[6], wB[6];
  {
    const float* a = dtw + ((size_t)kA*DI + c)*Rr;
    const float* bb = dtw + ((size_t)kB*DI + c)*Rr;
    #pragma unroll
    for (int r=0;r<6;r++) { wA[r]=a[r]; wB[r]=bb[r]; }
  }
  float biasA = dtb[kA*DI+c], biasB = dtb[kB*DI+c];
  float AA[16], AB[16];
  #pragma unroll
  for (int n=0;n<16;n++) {
    AA[n] = -__expf(A_log[((size_t)kA*DI + c)*Ns + n]) * 1.44269504f;
    AB[n] = -__expf(A_log[((size_t)kB*DI + c)*Ns + n]) * 1.44269504f;
  }
  const float* rbA = dblp + (size_t)(b*4+kA)*LL*RW;
  const float* rbB = dblp + (size_t)(b*4+kB)*LL*RW;
  float hA[16], hB[16];
  #pragma unroll
  for (int n=0;n<16;n++) { hA[n]=0.f; hB[n]=0.f; }
  float sA=0.f, sB=0.f;
  #pragma unroll
  for (int j=0;j<32;j++) {
    int pA = pbase + j*pstr;
    int pB = pbase + (31-j)*pstr;
    float rA[24], rB[24];
    {
      const float4* r4 = (const float4*)(rbA + (size_t)pA*RW);
      #pragma unroll
      for (int q=0;q<6;q++) *((float4*)&rA[4*q]) = r4[q];
      const float4* s4 = (const float4*)(rbB + (size_t)pB*RW);
      #pragma unroll
      for (int q=0;q<6;q++) *((float4*)&rB[4*q]) = s4[q];
    }
    float rawA = biasA, rawB = biasB;
    #pragma unroll
    for (int r=0;r<6;r++) { rawA += wA[r]*rA[r]; rawB += wB[r]*rB[r]; }
    float dtA = (rawA>20.f)?rawA:log1pf(__expf(rawA));
    float dtB = (rawB>20.f)?rawB:log1pf(__expf(rawB));
    float uA = v_t[((size_t)b*LL + pA)*DI + c];
    float uB = v_t[((size_t)b*LL + pB)*DI + c];
    float duA = dtA*uA, duB = dtB*uB;
    sA += dtA; sB += dtB;
    #pragma unroll
    for (int n=0;n<16;n++) {
      hA[n] = hA[n]*exp2f(dtA*AA[n]) + duA*rA[6+n];
      hB[n] = hB[n]*exp2f(dtB*AB[n]) + duB*rB[6+n];
    }
  }
  size_t baseA = ((size_t)segA*8 + (b*4+kA))*(DI*Ns) + (size_t)c*Ns;
  size_t baseB = ((size_t)segB*8 + (b*4+kB))*(DI*Ns) + (size_t)c*Ns;
  float4* oA = (float4*)(hend + baseA);
  float4* oB = (float4*)(hend + baseB);
  #pragma unroll
  for (int q=0;q<4;q++) {
    oA[q] = make_float4(hA[4*q],hA[4*q+1],hA[4*q+2],hA[4*q+3]);
    oB[q] = make_float4(hB[4*q],hB[4*q+1],hB[4*q+2],hB[4*q+3]);
  }
  sdt_o[((size_t)segA*8 + (b*4+kA))*DI + c] = sA;
  sdt_o[((size_t)segB*8 + (b*4+kB))*DI + c] = sB;
}

// sequential fix-up: hend -> h_init in place
__global__ __launch_bounds__(256) void k_fix(float* __restrict__ hend,
    const float* __restrict__ sdt, const float* __restrict__ A_log) {
  int t = blockIdx.x*256 + threadIdx.x;
  int n = t & 15; int cn = t >> 4; int c = cn % DI; int bk = cn / DI; int k = bk & 3;
  float A = -__expf(A_log[((size_t)k*DI + c)*Ns + n]);
  float hi = 0.f;
  #pragma unroll 8
  for (int s=0; s<SEG; s++) {
    float he = hend[(size_t)s*NBKCN + t];
    float P  = __expf(A * sdt[(size_t)s*(8*DI) + bk*DI + c]);
    hend[(size_t)s*NBKCN + t] = hi;
    hi = he + P*hi;
  }
}

// ---- scan pass B: rescan from h_init, merge pair y into ym rows ----
__global__ __launch_bounds__(192) void k_scanB(const float* __restrict__ v_t,
    const float* __restrict__ dblp, const float* __restrict__ dtw,
    const float* __restrict__ dtb, const float* __restrict__ A_log,
    const float* __restrict__ hinit, float* __restrict__ ym_a, float* __restrict__ ym_b) {
  int c = threadIdx.x;
  int s = blockIdx.x, pair = blockIdx.y, b = blockIdx.z;
  int kA = pair ? 1 : 0, kB = pair ? 3 : 2;
  int segA = s, segB = SEG-1-s;
  int pbase = pair ? ((s&1)*2048 + (s>>1)) : s*32;
  int pstr  = pair ? 64 : 1;
  float wA[6], wB[6];
  {
    const float* a = dtw + ((size_t)kA*DI + c)*Rr;
    const float* bb = dtw + ((size_t)kB*DI + c)*Rr;
    #pragma unroll
    for (int r=0;r<6;r++) { wA[r]=a[r]; wB[r]=bb[r]; }
  }
  float biasA = dtb[kA*DI+c], biasB = dtb[kB*DI+c];
  float AA[16], AB[16];
  #pragma unroll
  for (int n=0;n<16;n++) {
    AA[n] = -__expf(A_log[((size_t)kA*DI + c)*Ns + n]) * 1.44269504f;
    AB[n] = -__expf(A_log[((size_t)kB*DI + c)*Ns + n]) * 1.44269504f;
  }
  const float* rbA = dblp + (size_t)(b*4+kA)*LL*RW;
  const float* rbB = dblp + (size_t)(b*4+kB)*LL*RW;
  float hA[16], hB[16];
  {
    size_t baseA = ((size_t)segA*8 + (b*4+kA))*(DI*Ns) + (size_t)c*Ns;
    size_t baseB = ((size_t)segB*8 + (b*4+kB))*(DI*Ns) + (size_t)c*Ns;
    const float4* iA = (const float4*)(hinit + baseA);
    const float4* iB = (const float4*)(hinit + baseB);
    #pragma unroll
    for (int q=0;q<4;q++) {
      float4 v = iA[q]; hA[4*q]=v.x; hA[4*q+1]=v.y; hA[4*q+2]=v.z; hA[4*q+3]=v.w;
      float4 u = iB[q]; hB[4*q]=u.x; hB[4*q+1]=u.y; hB[4*q+2]=u.z; hB[4*q+3]=u.w;
    }
  }
  float yr[32];
  #pragma unroll
  for (int j=0;j<32;j++) {
    int pA = pbase + j*pstr;
    int pB = pbase + (31-j)*pstr;
    float rA[40], rB[40];
    {
      const float4* r4 = (const float4*)(rbA + (size_t)pA*RW);
      #pragma unroll
      for (int q=0;q<10;q++) *((float4*)&rA[4*q]) = r4[q];
      const float4* s4 = (const float4*)(rbB + (size_t)pB*RW);
      #pragma unroll
      for (int q=0;q<10;q++) *((float4*)&rB[4*q]) = s4[q];
    }
    float rawA = biasA, rawB = biasB;
    #pragma unroll
    for (int r=0;r<6;r++) { rawA += wA[r]*rA[r]; rawB += wB[r]*rB[r]; }
    float dtA = (rawA>20.f)?rawA:log1pf(__expf(rawA));
    float dtB = (rawB>20.f)?rawB:log1pf(__expf(rawB));
    float uA = v_t[((size_t)b*LL + pA)*DI + c];
    float uB = v_t[((size_t)b*LL + pB)*DI + c];
    float duA = dtA*uA, duB = dtB*uB;
    float yAv = 0.f, yBv = 0.f;
    #pragma unroll
    for (int n=0;n<16;n++) {
      hA[n] = hA[n]*exp2f(dtA*AA[n]) + duA*rA[6+n];
      yAv += hA[n]*rA[22+n];
      hB[n] = hB[n]*exp2f(dtB*AB[n]) + duB*rB[6+n];
      yBv += hB[n]*rB[22+n];
    }
    if (j<16) { yr[j] = yAv; yr[31-j] = yBv; }
    else      { yr[j] += yAv; yr[31-j] += yBv; }
  }
  float* ym = pair ? ym_b : ym_a;
  #pragma unroll
  for (int i=0;i<32;i++)
    ym[((size_t)b*LL + pbase + i*pstr)*DI + c] = yr[i];
}

// merge pairs + D-term + chanLN(192) -> yn_ct[b][c][l] via LDS transpose
#define MLT 32
__global__ __launch_bounds__(192) void k_merge_ln(const float* __restrict__ ym_a,
    const float* __restrict__ ym_b, const float* __restrict__ v_t,
    const float* __restrict__ Ds, const float* __restrict__ g,
    const float* __restrict__ be, float* __restrict__ yn_ct) {
  __shared__ float tile[DI*(MLT+1)];
  __shared__ float red[2][3];
  int c = threadIdx.x;
  int b = blockIdx.y;
  int l0 = blockIdx.x*MLT;
  float sd = Ds[c] + Ds[DI+c] + Ds[2*DI+c] + Ds[3*DI+c];
  float gg = g[c], bb = be[c];
  int wv = c >> 6, ln = c & 63;
  for (int i=0;i<MLT;i++) {
    size_t row = ((size_t)b*LL + l0 + i)*DI + c;
    float v = ym_a[row] + ym_b[row] + v_t[row]*sd;
    float s = v, s2 = v*v;
    #pragma unroll
    for (int d=1; d<64; d<<=1) { s += __shfl_xor(s,d); s2 += __shfl_xor(s2,d); }
    if (ln==0) { red[0][wv]=s; red[1][wv]=s2; }
    __syncthreads();
    float S  = red[0][0]+red[0][1]+red[0][2];
    float S2 = red[1][0]+red[1][1]+red[1][2];
    __syncthreads();
    float mu = S*(1.f/DI);
    float var = S2*(1.f/DI) - mu*mu;
    float r = rsqrtf(var + LNEPS);
    tile[c*(MLT+1) + i] = (v-mu)*r*gg + bb;
  }
  __syncthreads();
  #pragma unroll 4
  for (int it=0; it<MLT; it++) {
    int idx = it*DI + c;
    int cc = idx >> 5;
    int j  = idx & 31;
    yn_ct[((size_t)b*DI + cc)*LL + l0 + j] = tile[cc*(MLT+1) + j];
  }
}

// out_proj + skip, f32 out
__global__ __launch_bounds__(256) void k_outproj(const float* __restrict__ y,
    const float* __restrict__ w, const float* __restrict__ x1,
    const float* __restrict__ ss, float* __restrict__ out) {
  int l = blockIdx.x*256 + threadIdx.x;
  int o0 = blockIdx.y*8; int b = blockIdx.z;
  const float* yb = y + ((size_t)b*DI)*LL + l;
  const float* w0 = w + (size_t)o0*DI;
  float acc[8];
  #pragma unroll
  for (int q=0;q<8;q++) acc[q]=0.f;
  for (int i=0;i<DI;i++) {
    float yv = yb[(size_t)i*LL];
    #pragma unroll
    for (int q=0;q<8;q++) acc[q] += w0[(size_t)q*DI + i]*yv;
  }
  float sc = ss[0];
  const float* xb = x1 + ((size_t)b*HD + o0)*LL + l;
  float* ob = out + ((size_t)b*HD + o0)*LL + l;
  #pragma unroll
  for (int q=0;q<8;q++) ob[(size_t)q*LL] = acc[q] + xb[(size_t)q*LL]*sc;
}

extern "C" void kernel_launch(void* const* d_in, const int* in_sizes, int n_in,
                              void* d_out, int out_size, void* d_ws, size_t ws_size,
                              hipStream_t stream) {
  const float* x         = (const float*)d_in[0];
  const float* in_conv_w = (const float*)d_in[1];
  const float* ln1_g     = (const float*)d_in[2];
  const float* ln1_b     = (const float*)d_in[3];
  const float* in_proj_w = (const float*)d_in[4];
  const float* dw_w      = (const float*)d_in[5];
  const float* dw_b      = (const float*)d_in[6];
  const float* x_proj_w  = (const float*)d_in[7];
  const float* dt_proj_w = (const float*)d_in[8];
  const float* dt_proj_b = (const float*)d_in[9];
  const float* A_log     = (const float*)d_in[10];
  const float* Ds        = (const float*)d_in[11];
  const float* onorm_g   = (const float*)d_in[12];
  const float* onorm_b   = (const float*)d_in[13];
  const float* out_proj_w= (const float*)d_in[14];
  const float* skip_s    = (const float*)d_in[15];
  float* out = (float*)d_out;

  float* ws   = (float*)d_ws;
  float* x1   = ws;                  //  786432
  float* hp   = x1   + 786432;       // 1572864  (conv2 out; later yn_ct)
  float* v_t  = hp   + 1572864;      // 1572864
  float* dblp = v_t  + 1572864;      // 1310720
  float* hend = dblp + 1310720;      // 3145728
  float* sdt  = hend + 3145728;      //  196608
  float* ym_a = sdt  + 196608;       // 1572864
  float* ym_b = ym_a + 1572864;      // 1572864
  float* yn   = hp;                  // reuse

  dim3 blk(256);
  k_conv1x1<<<dim3(16, HD/8, Bb), blk, 0, stream>>>(x, in_conv_w, x1, HD, HD);
  k_chanln <<<dim3(Bb*LL/256), blk, 0, stream>>>(x1, ln1_g, ln1_b, HD);
  k_conv1x1<<<dim3(16, DI/8, Bb), blk, 0, stream>>>(x1, in_proj_w, hp, HD, DI);
  k_dwconv_silu_t<<<dim3(64, Bb), dim3(192), 0, stream>>>(hp, dw_w, dw_b, v_t);
  k_proj   <<<dim3(64, Bb), blk, 0, stream>>>(v_t, x_proj_w, dblp);
  k_scanA  <<<dim3(SEG, 2, Bb), dim3(192), 0, stream>>>(v_t, dblp, dt_proj_w, dt_proj_b, A_log, hend, sdt);
  k_fix    <<<dim3(NBKCN/256), blk, 0, stream>>>(hend, sdt, A_log);
  k_scanB  <<<dim3(SEG, 2, Bb), dim3(192), 0, stream>>>(v_t, dblp, dt_proj_w, dt_proj_b, A_log, hend, ym_a, ym_b);
  k_merge_ln<<<dim3(LL/MLT, Bb), dim3(192), 0, stream>>>(ym_a, ym_b, v_t, Ds, onorm_g, onorm_b, yn);
  k_outproj<<<dim3(16, HD/8, Bb), blk, 0, stream>>>(yn, out_proj_w, x1, skip_s, out);
}

// Round 5
// 496.821 us; speedup vs baseline: 1.2899x; 1.2899x over previous
//
#include <hip/hip_runtime.h>
#include <hip/hip_bf16.h>

#define Bb 2
#define HD 96
#define DI 192
#define LL 4096
#define Kd 4
#define Ns 16
#define Rr 6
#define SEG 256
#define SEGLEN 16
#define NBKCN (Bb*Kd*DI*Ns)   // 24576
#define LNEPS 1e-5f
#define RW 40                  // dblp row: 6 dt | 16 B | 16 C | 2 pad
#define LOG2E 1.44269504f

// 1x1 conv, 8 outputs/thread
__global__ __launch_bounds__(256) void k_conv1x1(const float* __restrict__ x,
    const float* __restrict__ w, float* __restrict__ out, int Cin, int Cout) {
  int l = blockIdx.x*256 + threadIdx.x;
  int o0 = blockIdx.y*8;
  int b = blockIdx.z;
  const float* xb = x + ((size_t)b*Cin)*LL + l;
  const float* w0 = w + (size_t)o0*Cin;
  float acc[8];
  #pragma unroll
  for (int q=0;q<8;q++) acc[q]=0.f;
  for (int i=0;i<Cin;i++) {
    float xv = xb[(size_t)i*LL];
    #pragma unroll
    for (int q=0;q<8;q++) acc[q] += w0[(size_t)q*Cin + i]*xv;
  }
  float* ob = out + ((size_t)b*Cout + o0)*LL + l;
  #pragma unroll
  for (int q=0;q<8;q++) ob[(size_t)q*LL] = acc[q];
}

// chanLN over 96 ch, parallel: block=(ltile32,b), threads 256 = 32 l x 8 cgroups
__global__ __launch_bounds__(256) void k_chanln96(float* __restrict__ t,
    const float* __restrict__ g, const float* __restrict__ be) {
  __shared__ float rs[2][32][9];
  int tid = threadIdx.x;
  int l = tid & 31, cg = tid >> 5;
  int l0 = blockIdx.x*32; int b = blockIdx.y;
  float* col = t + (size_t)b*HD*LL + l0 + l;
  float v[12];
  float s=0.f, s2=0.f;
  #pragma unroll
  for (int i=0;i<12;i++) {
    int c = cg*12 + i;
    float vv = col[(size_t)c*LL];
    v[i] = vv; s += vv; s2 += vv*vv;
  }
  rs[0][l][cg] = s; rs[1][l][cg] = s2;
  __syncthreads();
  float S=0.f, S2=0.f;
  #pragma unroll
  for (int q=0;q<8;q++) { S += rs[0][l][q]; S2 += rs[1][l][q]; }
  float mu = S*(1.f/HD);
  float var = S2*(1.f/HD) - mu*mu;
  float r = rsqrtf(var + LNEPS);
  #pragma unroll
  for (int i=0;i<12;i++) {
    int c = cg*12 + i;
    col[(size_t)c*LL] = (v[i]-mu)*r*g[c] + be[c];
  }
}

// depthwise 3x3 + bias + silu -> channel-last v_t[b][p][c]; d-quartered
// block=(h, dq, b), 192 thr: phase1 (w=t&63, dg=t>>6 covers 16 d each)
__global__ __launch_bounds__(192) void k_dwconv_silu_t(const float* __restrict__ hp,
    const float* __restrict__ wgt, const float* __restrict__ bias, float* __restrict__ v_t) {
  __shared__ float lds[48*65];
  int t = threadIdx.x;
  int w0 = t & 63, dg = t >> 6;
  int h = blockIdx.x, dq = blockIdx.y, b = blockIdx.z;
  for (int dd=0; dd<16; ++dd) {
    int dl = dg*16 + dd;          // 0..47
    int d = dq*48 + dl;
    const float* src = hp + ((size_t)b*DI + d)*LL;
    const float* wk = wgt + d*9;
    float acc = bias[d];
    #pragma unroll
    for (int dy=-1; dy<=1; dy++) {
      int hh = h+dy;
      if (hh < 0 || hh >= 64) continue;
      #pragma unroll
      for (int dx=-1; dx<=1; dx++) {
        int ww = w0+dx;
        if (ww < 0 || ww >= 64) continue;
        acc += wk[(dy+1)*3 + (dx+1)] * src[hh*64 + ww];
      }
    }
    lds[dl*65 + w0] = acc / (1.f + __expf(-acc));
  }
  __syncthreads();
  int hc = t % 48, ig = t / 48;   // 4 i-groups of 16
  for (int ii=0; ii<16; ii++) {
    int i = ig*16 + ii;
    v_t[((size_t)b*LL + h*64 + i)*DI + dq*48 + hc] = lds[hc*65 + i];
  }
}

// dblp[b][k][p][40] = W_k(38x192) . v_row(p); block=(ptile16,b), 256 thr = 4k x 16p x 4dg
__global__ __launch_bounds__(256) void k_proj(const float* __restrict__ v_t,
    const float* __restrict__ xpw, float* __restrict__ dblp) {
  __shared__ float lds[16*196];
  int t = threadIdx.x;
  int pt = blockIdx.x, b = blockIdx.y;
  const float4* src = (const float4*)(v_t + ((size_t)b*LL + pt*16)*DI);
  for (int idx=t; idx<768; idx+=256) {
    int row = idx/48, q = idx - row*48;
    *((float4*)&lds[row*196 + 4*q]) = src[idx];
  }
  __syncthreads();
  int k = t>>6, sub = t&63, p = sub>>2, dg = sub&3;
  int d0 = dg*10;
  int nd = (dg==3) ? 8 : 10;
  float acc[10];
  #pragma unroll
  for (int q=0;q<10;q++) acc[q]=0.f;
  const float4* W4 = (const float4*)(xpw + ((size_t)k*38 + d0)*DI);
  const float4* row4 = (const float4*)(lds + p*196);
  for (int c4=0;c4<48;c4++) {
    float4 xv = row4[c4];
    #pragma unroll
    for (int dd=0;dd<10;dd++) {
      if (dd < nd) {
        float4 wv = W4[(size_t)dd*48 + c4];
        acc[dd] += xv.x*wv.x + xv.y*wv.y + xv.z*wv.z + xv.w*wv.w;
      }
    }
  }
  float* o = dblp + (((size_t)b*4 + k)*LL + pt*16 + p)*RW + d0;
  for (int dd=0;dd<nd;dd++) o[dd] = acc[dd];
}

__device__ __forceinline__ void dir_map(int k, int s, int& pbase, int& pstr) {
  if (k==0)      { pbase = s*16;                          pstr = 1;   }
  else if (k==1) { pbase = (s&3)*1024 + (s>>2);           pstr = 64;  }
  else if (k==2) { pbase = 4095 - s*16;                   pstr = -1;  }
  else           { pbase = 4095 - (s&3)*1024 - (s>>2);    pstr = -64; }
}

// pass A: zero-init per-segment end state + sum(dt); block=(s,k,b), 192 thr (c)
__global__ __launch_bounds__(192) void k_scanA(const float* __restrict__ v_t,
    const float* __restrict__ dblp, const float* __restrict__ dtw,
    const float* __restrict__ dtb, const float* __restrict__ A_log,
    float* __restrict__ hend, float* __restrict__ sdt_o) {
  __shared__ float rows[SEGLEN*24];
  int t = threadIdx.x;
  int s = blockIdx.x, k = blockIdx.y, b = blockIdx.z;
  int bk = b*4 + k;
  int pbase, pstr; dir_map(k, s, pbase, pstr);
  if (t < 96) {
    int r = t/6, q = t - r*6;
    int p = pbase + r*pstr;
    const float4* src = (const float4*)(dblp + ((size_t)bk*LL + p)*RW);
    *((float4*)&rows[r*24 + 4*q]) = src[q];
  }
  int c = t;
  float w[6];
  {
    const float* wr = dtw + ((size_t)k*DI + c)*Rr;
    #pragma unroll
    for (int r=0;r<6;r++) w[r] = wr[r];
  }
  float bias = dtb[k*DI + c];
  float A2[16];
  {
    const float4* Ap = (const float4*)(A_log + ((size_t)k*DI + c)*Ns);
    #pragma unroll
    for (int q=0;q<4;q++) {
      float4 av = Ap[q];
      A2[4*q+0]=-__expf(av.x)*LOG2E; A2[4*q+1]=-__expf(av.y)*LOG2E;
      A2[4*q+2]=-__expf(av.z)*LOG2E; A2[4*q+3]=-__expf(av.w)*LOG2E;
    }
  }
  __syncthreads();
  float h[16];
  #pragma unroll
  for (int n=0;n<16;n++) h[n]=0.f;
  float sdt = 0.f;
  #pragma unroll
  for (int j=0;j<SEGLEN;j++) {
    const float* row = &rows[j*24];
    float raw = bias;
    #pragma unroll
    for (int r=0;r<6;r++) raw += w[r]*row[r];
    float dt = (raw>20.f) ? raw : log1pf(__expf(raw));
    float u = v_t[((size_t)b*LL + pbase + j*pstr)*DI + c];
    float du = dt*u;
    sdt += dt;
    #pragma unroll
    for (int n=0;n<16;n++)
      h[n] = h[n]*exp2f(dt*A2[n]) + du*row[6+n];
  }
  size_t base = ((size_t)s*8 + bk)*(DI*Ns) + (size_t)c*Ns;
  float4* o4 = (float4*)(hend + base);
  #pragma unroll
  for (int q=0;q<4;q++) o4[q] = make_float4(h[4*q],h[4*q+1],h[4*q+2],h[4*q+3]);
  sdt_o[((size_t)s*8 + bk)*DI + c] = sdt;
}

// fix-up: hend -> h_init in place (sequential over SEG, unroll-pipelined)
__global__ __launch_bounds__(256) void k_fix(float* __restrict__ hend,
    const float* __restrict__ sdt, const float* __restrict__ A_log) {
  int t = blockIdx.x*256 + threadIdx.x;
  int n = t & 15; int cn = t >> 4; int c = cn % DI; int bk = cn / DI; int k = bk & 3;
  float A = -__expf(A_log[((size_t)k*DI + c)*Ns + n]);
  float hi = 0.f;
  #pragma unroll 8
  for (int s=0; s<SEG; s++) {
    float he = hend[(size_t)s*NBKCN + t];
    float P  = __expf(A * sdt[(size_t)s*(8*DI) + bk*DI + c]);
    hend[(size_t)s*NBKCN + t] = hi;
    hi = he + P*hi;
  }
}

// pass B: rescan from h_init, emit y rows scattered to ORIGINAL positions
__global__ __launch_bounds__(192) void k_scanB(const float* __restrict__ v_t,
    const float* __restrict__ dblp, const float* __restrict__ dtw,
    const float* __restrict__ dtb, const float* __restrict__ A_log,
    const float* __restrict__ hinit, float* __restrict__ ym) {
  __shared__ float rows[SEGLEN*RW];
  int t = threadIdx.x;
  int s = blockIdx.x, k = blockIdx.y, b = blockIdx.z;
  int bk = b*4 + k;
  int pbase, pstr; dir_map(k, s, pbase, pstr);
  if (t < 160) {
    int r = t/10, q = t - r*10;
    int p = pbase + r*pstr;
    const float4* src = (const float4*)(dblp + ((size_t)bk*LL + p)*RW);
    *((float4*)&rows[r*RW + 4*q]) = src[q];
  }
  int c = t;
  float w[6];
  {
    const float* wr = dtw + ((size_t)k*DI + c)*Rr;
    #pragma unroll
    for (int r=0;r<6;r++) w[r] = wr[r];
  }
  float bias = dtb[k*DI + c];
  float A2[16];
  {
    const float4* Ap = (const float4*)(A_log + ((size_t)k*DI + c)*Ns);
    #pragma unroll
    for (int q=0;q<4;q++) {
      float4 av = Ap[q];
      A2[4*q+0]=-__expf(av.x)*LOG2E; A2[4*q+1]=-__expf(av.y)*LOG2E;
      A2[4*q+2]=-__expf(av.z)*LOG2E; A2[4*q+3]=-__expf(av.w)*LOG2E;
    }
  }
  float h[16];
  {
    size_t base = ((size_t)s*8 + bk)*(DI*Ns) + (size_t)c*Ns;
    const float4* i4 = (const float4*)(hinit + base);
    #pragma unroll
    for (int q=0;q<4;q++) {
      float4 v = i4[q];
      h[4*q]=v.x; h[4*q+1]=v.y; h[4*q+2]=v.z; h[4*q+3]=v.w;
    }
  }
  __syncthreads();
  float* ymk = ym + ((size_t)(k*Bb + b)*LL)*DI;
  #pragma unroll
  for (int j=0;j<SEGLEN;j++) {
    const float* row = &rows[j*RW];
    float raw = bias;
    #pragma unroll
    for (int r=0;r<6;r++) raw += w[r]*row[r];
    float dt = (raw>20.f) ? raw : log1pf(__expf(raw));
    int p = pbase + j*pstr;
    float u = v_t[((size_t)b*LL + p)*DI + c];
    float du = dt*u;
    float y = 0.f;
    #pragma unroll
    for (int n=0;n<16;n++) {
      h[n] = h[n]*exp2f(dt*A2[n]) + du*row[6+n];
      y += h[n]*row[22+n];
    }
    ymk[(size_t)p*DI + c] = y;
  }
}

// merge 4 dirs + D-term + chanLN(192) -> yn_ct[b][c][l] via LDS transpose
#define MLT 32
__global__ __launch_bounds__(192) void k_merge_ln(const float* __restrict__ ym,
    const float* __restrict__ v_t, const float* __restrict__ Ds,
    const float* __restrict__ g, const float* __restrict__ be, float* __restrict__ yn_ct) {
  __shared__ float tile[DI*(MLT+1)];
  __shared__ float red[2][3];
  int c = threadIdx.x;
  int b = blockIdx.y;
  int l0 = blockIdx.x*MLT;
  float sd = Ds[c] + Ds[DI+c] + Ds[2*DI+c] + Ds[3*DI+c];
  float gg = g[c], bb = be[c];
  int wv = c >> 6, ln = c & 63;
  for (int i=0;i<MLT;i++) {
    size_t row = ((size_t)b*LL + l0 + i)*DI + c;
    float v = ym[row] + ym[(size_t)2*LL*DI + row]
            + ym[(size_t)4*LL*DI + row] + ym[(size_t)6*LL*DI + row]
            + v_t[row]*sd;
    float s = v, s2 = v*v;
    #pragma unroll
    for (int d=1; d<64; d<<=1) { s += __shfl_xor(s,d); s2 += __shfl_xor(s2,d); }
    if (ln==0) { red[0][wv]=s; red[1][wv]=s2; }
    __syncthreads();
    float S  = red[0][0]+red[0][1]+red[0][2];
    float S2 = red[1][0]+red[1][1]+red[1][2];
    __syncthreads();
    float mu = S*(1.f/DI);
    float var = S2*(1.f/DI) - mu*mu;
    float r = rsqrtf(var + LNEPS);
    tile[c*(MLT+1) + i] = (v-mu)*r*gg + bb;
  }
  __syncthreads();
  #pragma unroll 4
  for (int it=0; it<MLT; it++) {
    int idx = it*DI + c;
    int cc = idx >> 5;
    int j  = idx & 31;
    yn_ct[((size_t)b*DI + cc)*LL + l0 + j] = tile[cc*(MLT+1) + j];
  }
}

// out_proj + skip, f32 out
__global__ __launch_bounds__(256) void k_outproj(const float* __restrict__ y,
    const float* __restrict__ w, const float* __restrict__ x1,
    const float* __restrict__ ss, float* __restrict__ out) {
  int l = blockIdx.x*256 + threadIdx.x;
  int o0 = blockIdx.y*8; int b = blockIdx.z;
  const float* yb = y + ((size_t)b*DI)*LL + l;
  const float* w0 = w + (size_t)o0*DI;
  float acc[8];
  #pragma unroll
  for (int q=0;q<8;q++) acc[q]=0.f;
  for (int i=0;i<DI;i++) {
    float yv = yb[(size_t)i*LL];
    #pragma unroll
    for (int q=0;q<8;q++) acc[q] += w0[(size_t)q*DI + i]*yv;
  }
  float sc = ss[0];
  const float* xb = x1 + ((size_t)b*HD + o0)*LL + l;
  float* ob = out + ((size_t)b*HD + o0)*LL + l;
  #pragma unroll
  for (int q=0;q<8;q++) ob[(size_t)q*LL] = acc[q] + xb[(size_t)q*LL]*sc;
}

extern "C" void kernel_launch(void* const* d_in, const int* in_sizes, int n_in,
                              void* d_out, int out_size, void* d_ws, size_t ws_size,
                              hipStream_t stream) {
  const float* x         = (const float*)d_in[0];
  const float* in_conv_w = (const float*)d_in[1];
  const float* ln1_g     = (const float*)d_in[2];
  const float* ln1_b     = (const float*)d_in[3];
  const float* in_proj_w = (const float*)d_in[4];
  const float* dw_w      = (const float*)d_in[5];
  const float* dw_b      = (const float*)d_in[6];
  const float* x_proj_w  = (const float*)d_in[7];
  const float* dt_proj_w = (const float*)d_in[8];
  const float* dt_proj_b = (const float*)d_in[9];
  const float* A_log     = (const float*)d_in[10];
  const float* Ds        = (const float*)d_in[11];
  const float* onorm_g   = (const float*)d_in[12];
  const float* onorm_b   = (const float*)d_in[13];
  const float* out_proj_w= (const float*)d_in[14];
  const float* skip_s    = (const float*)d_in[15];
  float* out = (float*)d_out;

  float* ws   = (float*)d_ws;
  float* x1   = ws;                  //   786,432
  float* hp   = x1   + 786432;       // 1,572,864  (conv2 out; later yn_ct)
  float* v_t  = hp   + 1572864;      // 1,572,864
  float* dblp = v_t  + 1572864;      // 1,310,720
  float* hend = dblp + 1310720;      // 6,291,456
  float* sdt  = hend + 6291456;      //   393,216
  float* ym   = sdt  + 393216;       // 6,291,456 (4 x [b][p][c])
  float* yn   = hp;                  // reuse

  dim3 blk(256);
  k_conv1x1<<<dim3(16, HD/8, Bb), blk, 0, stream>>>(x, in_conv_w, x1, HD, HD);
  k_chanln96<<<dim3(LL/32, Bb), blk, 0, stream>>>(x1, ln1_g, ln1_b);
  k_conv1x1<<<dim3(16, DI/8, Bb), blk, 0, stream>>>(x1, in_proj_w, hp, HD, DI);
  k_dwconv_silu_t<<<dim3(64, 4, Bb), dim3(192), 0, stream>>>(hp, dw_w, dw_b, v_t);
  k_proj   <<<dim3(LL/16, Bb), blk, 0, stream>>>(v_t, x_proj_w, dblp);
  k_scanA  <<<dim3(SEG, Kd, Bb), dim3(192), 0, stream>>>(v_t, dblp, dt_proj_w, dt_proj_b, A_log, hend, sdt);
  k_fix    <<<dim3(NBKCN/256), blk, 0, stream>>>(hend, sdt, A_log);
  k_scanB  <<<dim3(SEG, Kd, Bb), dim3(192), 0, stream>>>(v_t, dblp, dt_proj_w, dt_proj_b, A_log, hend, ym);
  k_merge_ln<<<dim3(LL/MLT, Bb), dim3(192), 0, stream>>>(ym, v_t, Ds, onorm_g, onorm_b, yn);
  k_outproj<<<dim3(16, HD/8, Bb), blk, 0, stream>>>(yn, out_proj_w, x1, skip_s, out);
}

// Round 6
// 399.459 us; speedup vs baseline: 1.6043x; 1.2437x over previous
//
#include <hip/hip_runtime.h>
#include <hip/hip_bf16.h>

#define Bb 2
#define HD 96
#define DI 192
#define LL 4096
#define Kd 4
#define Ns 16
#define Rr 6
#define SEG 256
#define SEGLEN 16
#define NBKCN (Bb*Kd*DI*Ns)   // 24576
#define LNEPS 1e-5f
#define RW 40                  // dblp row: 6 dt | 16 B | 16 C | 2 pad
#define LOG2E 1.44269504f

// 1x1 conv, 4 outputs/thread (o-tile 4 for occupancy)
__global__ __launch_bounds__(256) void k_conv1x1(const float* __restrict__ x,
    const float* __restrict__ w, float* __restrict__ out, int Cin, int Cout) {
  int l = blockIdx.x*256 + threadIdx.x;
  int o0 = blockIdx.y*4;
  int b = blockIdx.z;
  const float* xb = x + ((size_t)b*Cin)*LL + l;
  const float* w0 = w + (size_t)o0*Cin;
  float a0=0.f,a1=0.f,a2=0.f,a3=0.f;
  for (int i=0;i<Cin;i++) {
    float xv = xb[(size_t)i*LL];
    a0 += w0[i]*xv;
    a1 += w0[Cin+i]*xv;
    a2 += w0[2*Cin+i]*xv;
    a3 += w0[3*Cin+i]*xv;
  }
  float* ob = out + ((size_t)b*Cout + o0)*LL + l;
  ob[0]=a0; ob[LL]=a1; ob[2*(size_t)LL]=a2; ob[3*(size_t)LL]=a3;
}

// chanLN over 96 ch: block=(ltile16,b), 256 thr = 16 l x 16 cgroups(6c)
__global__ __launch_bounds__(256) void k_chanln96(float* __restrict__ t,
    const float* __restrict__ g, const float* __restrict__ be) {
  __shared__ float rs[2][16][17];
  int tid = threadIdx.x;
  int l = tid & 15, cg = tid >> 4;
  int l0 = blockIdx.x*16; int b = blockIdx.y;
  float* col = t + (size_t)b*HD*LL + l0 + l;
  float v[6];
  float s=0.f, s2=0.f;
  #pragma unroll
  for (int i=0;i<6;i++) {
    int c = cg*6 + i;
    float vv = col[(size_t)c*LL];
    v[i] = vv; s += vv; s2 += vv*vv;
  }
  rs[0][l][cg] = s; rs[1][l][cg] = s2;
  __syncthreads();
  float S=0.f, S2=0.f;
  #pragma unroll
  for (int q=0;q<16;q++) { S += rs[0][l][q]; S2 += rs[1][l][q]; }
  float mu = S*(1.f/HD);
  float var = S2*(1.f/HD) - mu*mu;
  float r = rsqrtf(var + LNEPS);
  #pragma unroll
  for (int i=0;i<6;i++) {
    int c = cg*6 + i;
    col[(size_t)c*LL] = (v[i]-mu)*r*g[c] + be[c];
  }
}

// depthwise 3x3 + bias + silu -> channel-last v_t[b][p][c]; 24-ch slabs
// block=(h, dq8, b), 192 thr
__global__ __launch_bounds__(192) void k_dwconv_silu_t(const float* __restrict__ hp,
    const float* __restrict__ wgt, const float* __restrict__ bias, float* __restrict__ v_t) {
  __shared__ float lds[24*65];
  int t = threadIdx.x;
  int w0 = t & 63, dg = t >> 6;       // dg 0..2, 8 ch each
  int h = blockIdx.x, dq = blockIdx.y, b = blockIdx.z;
  for (int dd=0; dd<8; ++dd) {
    int dl = dg*8 + dd;               // 0..23
    int d = dq*24 + dl;
    const float* src = hp + ((size_t)b*DI + d)*LL;
    const float* wk = wgt + d*9;
    float acc = bias[d];
    #pragma unroll
    for (int dy=-1; dy<=1; dy++) {
      int hh = h+dy;
      if (hh < 0 || hh >= 64) continue;
      #pragma unroll
      for (int dx=-1; dx<=1; dx++) {
        int ww = w0+dx;
        if (ww < 0 || ww >= 64) continue;
        acc += wk[(dy+1)*3 + (dx+1)] * src[hh*64 + ww];
      }
    }
    lds[dl*65 + w0] = acc / (1.f + __expf(-acc));
  }
  __syncthreads();
  int hc = t % 24, ig = t / 24;       // ig 0..7, 8 i each
  if (ig < 8) {
    for (int ii=0; ii<8; ii++) {
      int i = ig*8 + ii;
      v_t[((size_t)b*LL + h*64 + i)*DI + dq*24 + hc] = lds[hc*65 + i];
    }
  }
}

// dblp[b][k][p][40] = W_k(38x192).v_row(p); block=(ptile32,k,b), 256 thr = 32p x 8dg
__global__ __launch_bounds__(256) void k_proj(const float* __restrict__ v_t,
    const float* __restrict__ xpw, float* __restrict__ dblp) {
  __shared__ float lds[32*196];
  int t = threadIdx.x;
  int pt = blockIdx.x, k = blockIdx.y, b = blockIdx.z;
  const float4* src = (const float4*)(v_t + ((size_t)b*LL + pt*32)*DI);
  for (int idx=t; idx<32*48; idx+=256) {
    int row = idx/48, q = idx - row*48;
    *((float4*)&lds[row*196 + 4*q]) = src[idx];
  }
  __syncthreads();
  int p = t & 31, dg = t >> 5;
  int d0 = (dg<6) ? dg*5 : 30 + (dg-6)*4;   // waves 0-2: nd=5, wave 3: nd=4 (uniform)
  int nd = (dg<6) ? 5 : 4;
  float acc[5];
  #pragma unroll
  for (int q=0;q<5;q++) acc[q]=0.f;
  const float4* W4 = (const float4*)(xpw + ((size_t)k*38 + d0)*DI);
  const float4* row4 = (const float4*)(lds + p*196);
  for (int c4=0;c4<48;c4++) {
    float4 xv = row4[c4];
    #pragma unroll
    for (int dd=0;dd<5;dd++) {
      if (dd < nd) {
        float4 wv = W4[(size_t)dd*48 + c4];
        acc[dd] += xv.x*wv.x + xv.y*wv.y + xv.z*wv.z + xv.w*wv.w;
      }
    }
  }
  float* o = dblp + (((size_t)b*4 + k)*LL + pt*32 + p)*RW + d0;
  for (int dd=0;dd<nd;dd++) o[dd] = acc[dd];
}

__device__ __forceinline__ void dir_map(int k, int s, int& pbase, int& pstr) {
  if (k==0)      { pbase = s*16;                          pstr = 1;   }
  else if (k==1) { pbase = (s&3)*1024 + (s>>2);           pstr = 64;  }
  else if (k==2) { pbase = 4095 - s*16;                   pstr = -1;  }
  else           { pbase = 4095 - (s&3)*1024 - (s>>2);    pstr = -64; }
}

// pass A: zero-init per-segment end state + sum(dt); block=(s,k,b), 192 thr (c)
__global__ __launch_bounds__(192) void k_scanA(const float* __restrict__ v_t,
    const float* __restrict__ dblp, const float* __restrict__ dtw,
    const float* __restrict__ dtb, const float* __restrict__ A_log,
    float* __restrict__ hend, float* __restrict__ sdt_o) {
  __shared__ float rows[SEGLEN*24];
  int t = threadIdx.x;
  int s = blockIdx.x, k = blockIdx.y, b = blockIdx.z;
  int bk = b*4 + k;
  int pbase, pstr; dir_map(k, s, pbase, pstr);
  if (t < 96) {
    int r = t/6, q = t - r*6;
    int p = pbase + r*pstr;
    const float4* src = (const float4*)(dblp + ((size_t)bk*LL + p)*RW);
    *((float4*)&rows[r*24 + 4*q]) = src[q];
  }
  int c = t;
  float w[6];
  {
    const float* wr = dtw + ((size_t)k*DI + c)*Rr;
    #pragma unroll
    for (int r=0;r<6;r++) w[r] = wr[r];
  }
  float bias = dtb[k*DI + c];
  float A2[16];
  {
    const float4* Ap = (const float4*)(A_log + ((size_t)k*DI + c)*Ns);
    #pragma unroll
    for (int q=0;q<4;q++) {
      float4 av = Ap[q];
      A2[4*q+0]=-__expf(av.x)*LOG2E; A2[4*q+1]=-__expf(av.y)*LOG2E;
      A2[4*q+2]=-__expf(av.z)*LOG2E; A2[4*q+3]=-__expf(av.w)*LOG2E;
    }
  }
  __syncthreads();
  float h[16];
  #pragma unroll
  for (int n=0;n<16;n++) h[n]=0.f;
  float sdt = 0.f;
  #pragma unroll
  for (int j=0;j<SEGLEN;j++) {
    const float* row = &rows[j*24];
    float raw = bias;
    #pragma unroll
    for (int r=0;r<6;r++) raw += w[r]*row[r];
    float dt = (raw>20.f) ? raw : log1pf(__expf(raw));
    float u = v_t[((size_t)b*LL + pbase + j*pstr)*DI + c];
    float du = dt*u;
    sdt += dt;
    #pragma unroll
    for (int n=0;n<16;n++)
      h[n] = h[n]*exp2f(dt*A2[n]) + du*row[6+n];
  }
  size_t base = ((size_t)s*8 + bk)*(DI*Ns) + (size_t)c*Ns;
  float4* o4 = (float4*)(hend + base);
  #pragma unroll
  for (int q=0;q<4;q++) o4[q] = make_float4(h[4*q],h[4*q+1],h[4*q+2],h[4*q+3]);
  sdt_o[((size_t)s*8 + bk)*DI + c] = sdt;
}

// fix-up: hend -> h_init in place (sequential over SEG, unroll-pipelined)
__global__ __launch_bounds__(256) void k_fix(float* __restrict__ hend,
    const float* __restrict__ sdt, const float* __restrict__ A_log) {
  int t = blockIdx.x*256 + threadIdx.x;
  int n = t & 15; int cn = t >> 4; int c = cn % DI; int bk = cn / DI; int k = bk & 3;
  float A = -__expf(A_log[((size_t)k*DI + c)*Ns + n]);
  float hi = 0.f;
  #pragma unroll 8
  for (int s=0; s<SEG; s++) {
    float he = hend[(size_t)s*NBKCN + t];
    float P  = __expf(A * sdt[(size_t)s*(8*DI) + bk*DI + c]);
    hend[(size_t)s*NBKCN + t] = hi;
    hi = he + P*hi;
  }
}

// pass B: rescan from h_init, emit y rows scattered to ORIGINAL positions
__global__ __launch_bounds__(192) void k_scanB(const float* __restrict__ v_t,
    const float* __restrict__ dblp, const float* __restrict__ dtw,
    const float* __restrict__ dtb, const float* __restrict__ A_log,
    const float* __restrict__ hinit, float* __restrict__ ym) {
  __shared__ float rows[SEGLEN*RW];
  int t = threadIdx.x;
  int s = blockIdx.x, k = blockIdx.y, b = blockIdx.z;
  int bk = b*4 + k;
  int pbase, pstr; dir_map(k, s, pbase, pstr);
  if (t < 160) {
    int r = t/10, q = t - r*10;
    int p = pbase + r*pstr;
    const float4* src = (const float4*)(dblp + ((size_t)bk*LL + p)*RW);
    *((float4*)&rows[r*RW + 4*q]) = src[q];
  }
  int c = t;
  float w[6];
  {
    const float* wr = dtw + ((size_t)k*DI + c)*Rr;
    #pragma unroll
    for (int r=0;r<6;r++) w[r] = wr[r];
  }
  float bias = dtb[k*DI + c];
  float A2[16];
  {
    const float4* Ap = (const float4*)(A_log + ((size_t)k*DI + c)*Ns);
    #pragma unroll
    for (int q=0;q<4;q++) {
      float4 av = Ap[q];
      A2[4*q+0]=-__expf(av.x)*LOG2E; A2[4*q+1]=-__expf(av.y)*LOG2E;
      A2[4*q+2]=-__expf(av.z)*LOG2E; A2[4*q+3]=-__expf(av.w)*LOG2E;
    }
  }
  float h[16];
  {
    size_t base = ((size_t)s*8 + bk)*(DI*Ns) + (size_t)c*Ns;
    const float4* i4 = (const float4*)(hinit + base);
    #pragma unroll
    for (int q=0;q<4;q++) {
      float4 v = i4[q];
      h[4*q]=v.x; h[4*q+1]=v.y; h[4*q+2]=v.z; h[4*q+3]=v.w;
    }
  }
  __syncthreads();
  float* ymk = ym + ((size_t)(k*Bb + b)*LL)*DI;
  #pragma unroll
  for (int j=0;j<SEGLEN;j++) {
    const float* row = &rows[j*RW];
    float raw = bias;
    #pragma unroll
    for (int r=0;r<6;r++) raw += w[r]*row[r];
    float dt = (raw>20.f) ? raw : log1pf(__expf(raw));
    int p = pbase + j*pstr;
    float u = v_t[((size_t)b*LL + p)*DI + c];
    float du = dt*u;
    float y = 0.f;
    #pragma unroll
    for (int n=0;n<16;n++) {
      h[n] = h[n]*exp2f(dt*A2[n]) + du*row[6+n];
      y += h[n]*row[22+n];
    }
    ymk[(size_t)p*DI + c] = y;
  }
}

// merge 4 dirs + D-term + chanLN(192) -> yn_ct[b][c][l]; batched, 2 barriers total
#define MLT 16
__global__ __launch_bounds__(192) void k_merge_ln(const float* __restrict__ ym,
    const float* __restrict__ v_t, const float* __restrict__ Ds,
    const float* __restrict__ g, const float* __restrict__ be, float* __restrict__ yn_ct) {
  __shared__ float tile[DI*(MLT+1)];
  __shared__ float red[2][MLT][4];
  int c = threadIdx.x;
  int b = blockIdx.y;
  int l0 = blockIdx.x*MLT;
  float sd = Ds[c] + Ds[DI+c] + Ds[2*DI+c] + Ds[3*DI+c];
  float gg = g[c], bb = be[c];
  int wv = c >> 6, ln = c & 63;
  float v[MLT];
  #pragma unroll
  for (int i=0;i<MLT;i++) {
    size_t row = ((size_t)b*LL + l0 + i)*DI + c;
    float vv = ym[row] + ym[(size_t)2*LL*DI + row]
             + ym[(size_t)4*LL*DI + row] + ym[(size_t)6*LL*DI + row]
             + v_t[row]*sd;
    v[i] = vv;
    float s = vv, s2 = vv*vv;
    #pragma unroll
    for (int d=1; d<64; d<<=1) { s += __shfl_xor(s,d); s2 += __shfl_xor(s2,d); }
    if (ln==0) { red[0][i][wv]=s; red[1][i][wv]=s2; }
  }
  __syncthreads();
  #pragma unroll
  for (int i=0;i<MLT;i++) {
    float S  = red[0][i][0]+red[0][i][1]+red[0][i][2];
    float S2 = red[1][i][0]+red[1][i][1]+red[1][i][2];
    float mu = S*(1.f/DI);
    float var = S2*(1.f/DI) - mu*mu;
    float r = rsqrtf(var + LNEPS);
    tile[c*(MLT+1) + i] = (v[i]-mu)*r*gg + bb;
  }
  __syncthreads();
  #pragma unroll
  for (int it=0; it<MLT; it++) {
    int idx = it*DI + c;
    int cc = idx >> 4;
    int j  = idx & 15;
    yn_ct[((size_t)b*DI + cc)*LL + l0 + j] = tile[cc*(MLT+1) + j];
  }
}

// out_proj (4 o/thread) + skip, f32 out
__global__ __launch_bounds__(256) void k_outproj(const float* __restrict__ y,
    const float* __restrict__ w, const float* __restrict__ x1,
    const float* __restrict__ ss, float* __restrict__ out) {
  int l = blockIdx.x*256 + threadIdx.x;
  int o0 = blockIdx.y*4; int b = blockIdx.z;
  const float* yb = y + ((size_t)b*DI)*LL + l;
  const float* w0 = w + (size_t)o0*DI;
  float a0=0.f,a1=0.f,a2=0.f,a3=0.f;
  for (int i=0;i<DI;i++) {
    float yv = yb[(size_t)i*LL];
    a0+=w0[i]*yv; a1+=w0[DI+i]*yv; a2+=w0[2*DI+i]*yv; a3+=w0[3*DI+i]*yv;
  }
  float sc = ss[0];
  const float* xb = x1 + ((size_t)b*HD + o0)*LL + l;
  float* ob = out + ((size_t)b*HD + o0)*LL + l;
  ob[0]          = a0 + xb[0]*sc;
  ob[LL]         = a1 + xb[LL]*sc;
  ob[2*(size_t)LL] = a2 + xb[2*(size_t)LL]*sc;
  ob[3*(size_t)LL] = a3 + xb[3*(size_t)LL]*sc;
}

extern "C" void kernel_launch(void* const* d_in, const int* in_sizes, int n_in,
                              void* d_out, int out_size, void* d_ws, size_t ws_size,
                              hipStream_t stream) {
  const float* x         = (const float*)d_in[0];
  const float* in_conv_w = (const float*)d_in[1];
  const float* ln1_g     = (const float*)d_in[2];
  const float* ln1_b     = (const float*)d_in[3];
  const float* in_proj_w = (const float*)d_in[4];
  const float* dw_w      = (const float*)d_in[5];
  const float* dw_b      = (const float*)d_in[6];
  const float* x_proj_w  = (const float*)d_in[7];
  const float* dt_proj_w = (const float*)d_in[8];
  const float* dt_proj_b = (const float*)d_in[9];
  const float* A_log     = (const float*)d_in[10];
  const float* Ds        = (const float*)d_in[11];
  const float* onorm_g   = (const float*)d_in[12];
  const float* onorm_b   = (const float*)d_in[13];
  const float* out_proj_w= (const float*)d_in[14];
  const float* skip_s    = (const float*)d_in[15];
  float* out = (float*)d_out;

  float* ws   = (float*)d_ws;
  float* x1   = ws;                  //   786,432
  float* hp   = x1   + 786432;       // 1,572,864  (conv2 out; later yn_ct)
  float* v_t  = hp   + 1572864;      // 1,572,864
  float* dblp = v_t  + 1572864;      // 1,310,720
  float* hend = dblp + 1310720;      // 6,291,456
  float* sdt  = hend + 6291456;      //   393,216
  float* ym   = sdt  + 393216;       // 6,291,456 (4 x [b][p][c])
  float* yn   = hp;                  // reuse

  dim3 blk(256);
  k_conv1x1<<<dim3(16, HD/4, Bb), blk, 0, stream>>>(x, in_conv_w, x1, HD, HD);
  k_chanln96<<<dim3(LL/16, Bb), blk, 0, stream>>>(x1, ln1_g, ln1_b);
  k_conv1x1<<<dim3(16, DI/4, Bb), blk, 0, stream>>>(x1, in_proj_w, hp, HD, DI);
  k_dwconv_silu_t<<<dim3(64, 8, Bb), dim3(192), 0, stream>>>(hp, dw_w, dw_b, v_t);
  k_proj   <<<dim3(LL/32, Kd, Bb), blk, 0, stream>>>(v_t, x_proj_w, dblp);
  k_scanA  <<<dim3(SEG, Kd, Bb), dim3(192), 0, stream>>>(v_t, dblp, dt_proj_w, dt_proj_b, A_log, hend, sdt);
  k_fix    <<<dim3(NBKCN/256), blk, 0, stream>>>(hend, sdt, A_log);
  k_scanB  <<<dim3(SEG, Kd, Bb), dim3(192), 0, stream>>>(v_t, dblp, dt_proj_w, dt_proj_b, A_log, hend, ym);
  k_merge_ln<<<dim3(LL/MLT, Bb), dim3(192), 0, stream>>>(ym, v_t, Ds, onorm_g, onorm_b, yn);
  k_outproj<<<dim3(16, HD/4, Bb), blk, 0, stream>>>(yn, out_proj_w, x1, skip_s, out);
}

// Round 7
// 311.621 us; speedup vs baseline: 2.0565x; 1.2819x over previous
//
#include <hip/hip_runtime.h>
#include <hip/hip_bf16.h>

#define Bb 2
#define HD 96
#define DI 192
#define LL 4096
#define Kd 4
#define Ns 16
#define Rr 6
#define SEG 256
#define SEGLEN 16
#define NBKCN (Bb*Kd*DI*Ns)   // 24576
#define LNEPS 1e-5f
#define RW 40                  // dblp row: 6 dt | 2 pad | 16 B | 16 C
#define LOG2E 1.44269504f

// 1x1 conv, 4 outputs/thread
__global__ __launch_bounds__(256) void k_conv1x1(const float* __restrict__ x,
    const float* __restrict__ w, float* __restrict__ out, int Cin, int Cout) {
  int l = blockIdx.x*256 + threadIdx.x;
  int o0 = blockIdx.y*4;
  int b = blockIdx.z;
  const float* xb = x + ((size_t)b*Cin)*LL + l;
  const float* w0 = w + (size_t)o0*Cin;
  float a0=0.f,a1=0.f,a2=0.f,a3=0.f;
  for (int i=0;i<Cin;i++) {
    float xv = xb[(size_t)i*LL];
    a0 += w0[i]*xv;
    a1 += w0[Cin+i]*xv;
    a2 += w0[2*Cin+i]*xv;
    a3 += w0[3*Cin+i]*xv;
  }
  float* ob = out + ((size_t)b*Cout + o0)*LL + l;
  ob[0]=a0; ob[LL]=a1; ob[2*(size_t)LL]=a2; ob[3*(size_t)LL]=a3;
}

// chanLN over 96 ch: block=(ltile16,b), 256 thr = 16 l x 16 cgroups(6c)
__global__ __launch_bounds__(256) void k_chanln96(float* __restrict__ t,
    const float* __restrict__ g, const float* __restrict__ be) {
  __shared__ float rs[2][16][17];
  int tid = threadIdx.x;
  int l = tid & 15, cg = tid >> 4;
  int l0 = blockIdx.x*16; int b = blockIdx.y;
  float* col = t + (size_t)b*HD*LL + l0 + l;
  float v[6];
  float s=0.f, s2=0.f;
  #pragma unroll
  for (int i=0;i<6;i++) {
    int c = cg*6 + i;
    float vv = col[(size_t)c*LL];
    v[i] = vv; s += vv; s2 += vv*vv;
  }
  rs[0][l][cg] = s; rs[1][l][cg] = s2;
  __syncthreads();
  float S=0.f, S2=0.f;
  #pragma unroll
  for (int q=0;q<16;q++) { S += rs[0][l][q]; S2 += rs[1][l][q]; }
  float mu = S*(1.f/HD);
  float var = S2*(1.f/HD) - mu*mu;
  float r = rsqrtf(var + LNEPS);
  #pragma unroll
  for (int i=0;i<6;i++) {
    int c = cg*6 + i;
    col[(size_t)c*LL] = (v[i]-mu)*r*g[c] + be[c];
  }
}

// depthwise 3x3 + bias + silu -> channel-last v_t[b][p][c]; 24-ch slabs
__global__ __launch_bounds__(192) void k_dwconv_silu_t(const float* __restrict__ hp,
    const float* __restrict__ wgt, const float* __restrict__ bias, float* __restrict__ v_t) {
  __shared__ float lds[24*65];
  int t = threadIdx.x;
  int w0 = t & 63, dg = t >> 6;
  int h = blockIdx.x, dq = blockIdx.y, b = blockIdx.z;
  for (int dd=0; dd<8; ++dd) {
    int dl = dg*8 + dd;
    int d = dq*24 + dl;
    const float* src = hp + ((size_t)b*DI + d)*LL;
    const float* wk = wgt + d*9;
    float acc = bias[d];
    #pragma unroll
    for (int dy=-1; dy<=1; dy++) {
      int hh = h+dy;
      if (hh < 0 || hh >= 64) continue;
      #pragma unroll
      for (int dx=-1; dx<=1; dx++) {
        int ww = w0+dx;
        if (ww < 0 || ww >= 64) continue;
        acc += wk[(dy+1)*3 + (dx+1)] * src[hh*64 + ww];
      }
    }
    lds[dl*65 + w0] = acc / (1.f + __expf(-acc));
  }
  __syncthreads();
  int hc = t % 24, ig = t / 24;
  if (ig < 8) {
    for (int ii=0; ii<8; ii++) {
      int i = ig*8 + ii;
      v_t[((size_t)b*LL + h*64 + i)*DI + dq*24 + hc] = lds[hc*65 + i];
    }
  }
}

// dblp[b][k][p][40] = W_k(38x192).v_row(p); padded layout 6|2|16|16
__global__ __launch_bounds__(256) void k_proj(const float* __restrict__ v_t,
    const float* __restrict__ xpw, float* __restrict__ dblp) {
  __shared__ float lds[32*196];
  int t = threadIdx.x;
  int pt = blockIdx.x, k = blockIdx.y, b = blockIdx.z;
  const float4* src = (const float4*)(v_t + ((size_t)b*LL + pt*32)*DI);
  for (int idx=t; idx<32*48; idx+=256) {
    int row = idx/48, q = idx - row*48;
    *((float4*)&lds[row*196 + 4*q]) = src[idx];
  }
  __syncthreads();
  int p = t & 31, dg = t >> 5;
  int d0 = (dg<6) ? dg*5 : 30 + (dg-6)*4;
  int nd = (dg<6) ? 5 : 4;
  float acc[5];
  #pragma unroll
  for (int q=0;q<5;q++) acc[q]=0.f;
  const float4* W4 = (const float4*)(xpw + ((size_t)k*38 + d0)*DI);
  const float4* row4 = (const float4*)(lds + p*196);
  for (int c4=0;c4<48;c4++) {
    float4 xv = row4[c4];
    #pragma unroll
    for (int dd=0;dd<5;dd++) {
      if (dd < nd) {
        float4 wv = W4[(size_t)dd*48 + c4];
        acc[dd] += xv.x*wv.x + xv.y*wv.y + xv.z*wv.z + xv.w*wv.w;
      }
    }
  }
  float* o = dblp + (((size_t)b*4 + k)*LL + pt*32 + p)*RW;
  for (int dd=0;dd<nd;dd++) {
    int d = d0 + dd;
    o[d + ((d>=6)?2:0)] = acc[dd];
  }
}

__device__ __forceinline__ void dir_map(int k, int s, int& pbase, int& pstr) {
  if (k==0)      { pbase = s*16;                          pstr = 1;   }
  else if (k==1) { pbase = (s&3)*1024 + (s>>2);           pstr = 64;  }
  else if (k==2) { pbase = 4095 - s*16;                   pstr = -1;  }
  else           { pbase = 4095 - (s&3)*1024 - (s>>2);    pstr = -64; }
}

__device__ __forceinline__ float softplus_f(float raw) {
  float e = __expf(raw);
  float l = __logf(1.f + e);
  return (raw > 20.f) ? raw : l;
}

// pass A: 2 segments per 384-thr block; u + dblp rows LDS-staged
__global__ __launch_bounds__(384) void k_scanA(const float* __restrict__ v_t,
    const float* __restrict__ dblp, const float* __restrict__ dtw,
    const float* __restrict__ dtb, const float* __restrict__ A_log,
    float* __restrict__ hend, float* __restrict__ sdt_o) {
  __shared__ float uld[2][SEGLEN][DI];
  __shared__ float rows[2][SEGLEN][24];
  int t = threadIdx.x;
  int sub = t/192, tl = t - sub*192;
  int s = blockIdx.x*2 + sub;
  int k = blockIdx.y, b = blockIdx.z;
  int bk = b*4 + k;
  int pbase, pstr; dir_map(k, s, pbase, pstr);
  // stage u (coalesced) and first 24 floats of each dblp row (dt|pad|B)
  for (int j=0;j<SEGLEN;j++)
    uld[sub][j][tl] = v_t[((size_t)b*LL + pbase + j*pstr)*DI + tl];
  if (tl < 96) {
    int r = tl/6, q = tl - r*6;
    const float4* src = (const float4*)(dblp + ((size_t)bk*LL + pbase + r*pstr)*RW);
    *((float4*)&rows[sub][r][4*q]) = src[q];
  }
  int c = tl;
  float w[6];
  {
    const float* wr = dtw + ((size_t)k*DI + c)*Rr;
    #pragma unroll
    for (int r=0;r<6;r++) w[r] = wr[r];
  }
  float bias = dtb[k*DI + c];
  float A2[16];
  {
    const float4* Ap = (const float4*)(A_log + ((size_t)k*DI + c)*Ns);
    #pragma unroll
    for (int q=0;q<4;q++) {
      float4 av = Ap[q];
      A2[4*q+0]=-__expf(av.x)*LOG2E; A2[4*q+1]=-__expf(av.y)*LOG2E;
      A2[4*q+2]=-__expf(av.z)*LOG2E; A2[4*q+3]=-__expf(av.w)*LOG2E;
    }
  }
  __syncthreads();
  float h[16];
  #pragma unroll
  for (int n=0;n<16;n++) h[n]=0.f;
  float sdt = 0.f;
  #pragma unroll 2
  for (int j=0;j<SEGLEN;j++) {
    const float* row = &rows[sub][j][0];
    float4 d0 = *((const float4*)row);
    float2 d1 = *((const float2*)(row+4));
    float raw = bias + w[0]*d0.x + w[1]*d0.y + w[2]*d0.z + w[3]*d0.w
              + w[4]*d1.x + w[5]*d1.y;
    float dt = softplus_f(raw);
    float du = dt * uld[sub][j][c];
    sdt += dt;
    const float4* Bv = (const float4*)(row+8);
    #pragma unroll
    for (int q=0;q<4;q++) {
      float4 bv = Bv[q];
      h[4*q+0] = h[4*q+0]*__builtin_amdgcn_exp2f(dt*A2[4*q+0]) + du*bv.x;
      h[4*q+1] = h[4*q+1]*__builtin_amdgcn_exp2f(dt*A2[4*q+1]) + du*bv.y;
      h[4*q+2] = h[4*q+2]*__builtin_amdgcn_exp2f(dt*A2[4*q+2]) + du*bv.z;
      h[4*q+3] = h[4*q+3]*__builtin_amdgcn_exp2f(dt*A2[4*q+3]) + du*bv.w;
    }
  }
  // hend layout [s][bk][n][c] -> coalesced stores
  float* ho = hend + ((size_t)s*8 + bk)*(DI*Ns) + c;
  #pragma unroll
  for (int n=0;n<16;n++) ho[(size_t)n*DI] = h[n];
  sdt_o[((size_t)s*8 + bk)*DI + c] = sdt;
}

// fix-up: hend -> h_init in place; t = bk*3072 + n*192 + c
__global__ __launch_bounds__(256) void k_fix(float* __restrict__ hend,
    const float* __restrict__ sdt, const float* __restrict__ A_log) {
  int t = blockIdx.x*256 + threadIdx.x;
  int c = t % DI;
  int nn = (t / DI) & 15;
  int bk = t / (DI*Ns);
  int k = bk & 3;
  float A = -__expf(A_log[((size_t)k*DI + c)*Ns + nn]);
  float hi = 0.f;
  #pragma unroll 8
  for (int s=0; s<SEG; s++) {
    float he = hend[(size_t)s*NBKCN + t];
    float P  = __expf(A * sdt[(size_t)s*(8*DI) + bk*DI + c]);
    hend[(size_t)s*NBKCN + t] = hi;
    hi = he + P*hi;
  }
}

// pass B: rescan from h_init, emit y scattered to ORIGINAL positions
__global__ __launch_bounds__(384) void k_scanB(const float* __restrict__ v_t,
    const float* __restrict__ dblp, const float* __restrict__ dtw,
    const float* __restrict__ dtb, const float* __restrict__ A_log,
    const float* __restrict__ hinit, float* __restrict__ ym) {
  __shared__ float uld[2][SEGLEN][DI];
  __shared__ float rows[2][SEGLEN][RW];
  int t = threadIdx.x;
  int sub = t/192, tl = t - sub*192;
  int s = blockIdx.x*2 + sub;
  int k = blockIdx.y, b = blockIdx.z;
  int bk = b*4 + k;
  int pbase, pstr; dir_map(k, s, pbase, pstr);
  for (int j=0;j<SEGLEN;j++)
    uld[sub][j][tl] = v_t[((size_t)b*LL + pbase + j*pstr)*DI + tl];
  if (tl < 160) {
    int r = tl/10, q = tl - r*10;
    const float4* src = (const float4*)(dblp + ((size_t)bk*LL + pbase + r*pstr)*RW);
    *((float4*)&rows[sub][r][4*q]) = src[q];
  }
  int c = tl;
  float w[6];
  {
    const float* wr = dtw + ((size_t)k*DI + c)*Rr;
    #pragma unroll
    for (int r=0;r<6;r++) w[r] = wr[r];
  }
  float bias = dtb[k*DI + c];
  float A2[16];
  {
    const float4* Ap = (const float4*)(A_log + ((size_t)k*DI + c)*Ns);
    #pragma unroll
    for (int q=0;q<4;q++) {
      float4 av = Ap[q];
      A2[4*q+0]=-__expf(av.x)*LOG2E; A2[4*q+1]=-__expf(av.y)*LOG2E;
      A2[4*q+2]=-__expf(av.z)*LOG2E; A2[4*q+3]=-__expf(av.w)*LOG2E;
    }
  }
  float h[16];
  {
    const float* hi = hinit + ((size_t)s*8 + bk)*(DI*Ns) + c;
    #pragma unroll
    for (int n=0;n<16;n++) h[n] = hi[(size_t)n*DI];
  }
  __syncthreads();
  float* ymk = ym + ((size_t)(k*Bb + b)*LL)*DI;
  #pragma unroll 2
  for (int j=0;j<SEGLEN;j++) {
    const float* row = &rows[sub][j][0];
    float4 d0 = *((const float4*)row);
    float2 d1 = *((const float2*)(row+4));
    float raw = bias + w[0]*d0.x + w[1]*d0.y + w[2]*d0.z + w[3]*d0.w
              + w[4]*d1.x + w[5]*d1.y;
    float dt = softplus_f(raw);
    float du = dt * uld[sub][j][c];
    const float4* Bv = (const float4*)(row+8);
    const float4* Cv = (const float4*)(row+24);
    float y = 0.f;
    #pragma unroll
    for (int q=0;q<4;q++) {
      float4 bv = Bv[q];
      float4 cv = Cv[q];
      h[4*q+0] = h[4*q+0]*__builtin_amdgcn_exp2f(dt*A2[4*q+0]) + du*bv.x;
      h[4*q+1] = h[4*q+1]*__builtin_amdgcn_exp2f(dt*A2[4*q+1]) + du*bv.y;
      h[4*q+2] = h[4*q+2]*__builtin_amdgcn_exp2f(dt*A2[4*q+2]) + du*bv.z;
      h[4*q+3] = h[4*q+3]*__builtin_amdgcn_exp2f(dt*A2[4*q+3]) + du*bv.w;
      y += h[4*q+0]*cv.x + h[4*q+1]*cv.y + h[4*q+2]*cv.z + h[4*q+3]*cv.w;
    }
    int p = pbase + j*pstr;
    ymk[(size_t)p*DI + c] = y;
  }
}

// merge 4 dirs + D-term + chanLN(192) -> yn_ct[b][c][l]
#define MLT 16
__global__ __launch_bounds__(192) void k_merge_ln(const float* __restrict__ ym,
    const float* __restrict__ v_t, const float* __restrict__ Ds,
    const float* __restrict__ g, const float* __restrict__ be, float* __restrict__ yn_ct) {
  __shared__ float tile[DI*(MLT+1)];
  __shared__ float red[2][MLT][4];
  int c = threadIdx.x;
  int b = blockIdx.y;
  int l0 = blockIdx.x*MLT;
  float sd = Ds[c] + Ds[DI+c] + Ds[2*DI+c] + Ds[3*DI+c];
  float gg = g[c], bb = be[c];
  int wv = c >> 6, ln = c & 63;
  float v[MLT];
  #pragma unroll
  for (int i=0;i<MLT;i++) {
    size_t row = ((size_t)b*LL + l0 + i)*DI + c;
    float vv = ym[row] + ym[(size_t)2*LL*DI + row]
             + ym[(size_t)4*LL*DI + row] + ym[(size_t)6*LL*DI + row]
             + v_t[row]*sd;
    v[i] = vv;
    float s = vv, s2 = vv*vv;
    #pragma unroll
    for (int d=1; d<64; d<<=1) { s += __shfl_xor(s,d); s2 += __shfl_xor(s2,d); }
    if (ln==0) { red[0][i][wv]=s; red[1][i][wv]=s2; }
  }
  __syncthreads();
  #pragma unroll
  for (int i=0;i<MLT;i++) {
    float S  = red[0][i][0]+red[0][i][1]+red[0][i][2];
    float S2 = red[1][i][0]+red[1][i][1]+red[1][i][2];
    float mu = S*(1.f/DI);
    float var = S2*(1.f/DI) - mu*mu;
    float r = rsqrtf(var + LNEPS);
    tile[c*(MLT+1) + i] = (v[i]-mu)*r*gg + bb;
  }
  __syncthreads();
  #pragma unroll
  for (int it=0; it<MLT; it++) {
    int idx = it*DI + c;
    int cc = idx >> 4;
    int j  = idx & 15;
    yn_ct[((size_t)b*DI + cc)*LL + l0 + j] = tile[cc*(MLT+1) + j];
  }
}

// out_proj (4 o/thread) + skip, f32 out
__global__ __launch_bounds__(256) void k_outproj(const float* __restrict__ y,
    const float* __restrict__ w, const float* __restrict__ x1,
    const float* __restrict__ ss, float* __restrict__ out) {
  int l = blockIdx.x*256 + threadIdx.x;
  int o0 = blockIdx.y*4; int b = blockIdx.z;
  const float* yb = y + ((size_t)b*DI)*LL + l;
  const float* w0 = w + (size_t)o0*DI;
  float a0=0.f,a1=0.f,a2=0.f,a3=0.f;
  for (int i=0;i<DI;i++) {
    float yv = yb[(size_t)i*LL];
    a0+=w0[i]*yv; a1+=w0[DI+i]*yv; a2+=w0[2*DI+i]*yv; a3+=w0[3*DI+i]*yv;
  }
  float sc = ss[0];
  const float* xb = x1 + ((size_t)b*HD + o0)*LL + l;
  float* ob = out + ((size_t)b*HD + o0)*LL + l;
  ob[0]          = a0 + xb[0]*sc;
  ob[LL]         = a1 + xb[LL]*sc;
  ob[2*(size_t)LL] = a2 + xb[2*(size_t)LL]*sc;
  ob[3*(size_t)LL] = a3 + xb[3*(size_t)LL]*sc;
}

extern "C" void kernel_launch(void* const* d_in, const int* in_sizes, int n_in,
                              void* d_out, int out_size, void* d_ws, size_t ws_size,
                              hipStream_t stream) {
  const float* x         = (const float*)d_in[0];
  const float* in_conv_w = (const float*)d_in[1];
  const float* ln1_g     = (const float*)d_in[2];
  const float* ln1_b     = (const float*)d_in[3];
  const float* in_proj_w = (const float*)d_in[4];
  const float* dw_w      = (const float*)d_in[5];
  const float* dw_b      = (const float*)d_in[6];
  const float* x_proj_w  = (const float*)d_in[7];
  const float* dt_proj_w = (const float*)d_in[8];
  const float* dt_proj_b = (const float*)d_in[9];
  const float* A_log     = (const float*)d_in[10];
  const float* Ds        = (const float*)d_in[11];
  const float* onorm_g   = (const float*)d_in[12];
  const float* onorm_b   = (const float*)d_in[13];
  const float* out_proj_w= (const float*)d_in[14];
  const float* skip_s    = (const float*)d_in[15];
  float* out = (float*)d_out;

  float* ws   = (float*)d_ws;
  float* x1   = ws;                  //   786,432
  float* hp   = x1   + 786432;       // 1,572,864  (conv2 out; later yn_ct)
  float* v_t  = hp   + 1572864;      // 1,572,864
  float* dblp = v_t  + 1572864;      // 1,310,720
  float* hend = dblp + 1310720;      // 6,291,456
  float* sdt  = hend + 6291456;      //   393,216
  float* ym   = sdt  + 393216;       // 6,291,456 (4 x [b][p][c])
  float* yn   = hp;                  // reuse

  dim3 blk(256);
  k_conv1x1<<<dim3(16, HD/4, Bb), blk, 0, stream>>>(x, in_conv_w, x1, HD, HD);
  k_chanln96<<<dim3(LL/16, Bb), blk, 0, stream>>>(x1, ln1_g, ln1_b);
  k_conv1x1<<<dim3(16, DI/4, Bb), blk, 0, stream>>>(x1, in_proj_w, hp, HD, DI);
  k_dwconv_silu_t<<<dim3(64, 8, Bb), dim3(192), 0, stream>>>(hp, dw_w, dw_b, v_t);
  k_proj   <<<dim3(LL/32, Kd, Bb), blk, 0, stream>>>(v_t, x_proj_w, dblp);
  k_scanA  <<<dim3(SEG/2, Kd, Bb), dim3(384), 0, stream>>>(v_t, dblp, dt_proj_w, dt_proj_b, A_log, hend, sdt);
  k_fix    <<<dim3(NBKCN/256), blk, 0, stream>>>(hend, sdt, A_log);
  k_scanB  <<<dim3(SEG/2, Kd, Bb), dim3(384), 0, stream>>>(v_t, dblp, dt_proj_w, dt_proj_b, A_log, hend, ym);
  k_merge_ln<<<dim3(LL/MLT, Bb), dim3(192), 0, stream>>>(ym, v_t, Ds, onorm_g, onorm_b, yn);
  k_outproj<<<dim3(16, HD/4, Bb), blk, 0, stream>>>(yn, out_proj_w, x1, skip_s, out);
}

// Round 8
// 287.069 us; speedup vs baseline: 2.2323x; 1.0855x over previous
//
#include <hip/hip_runtime.h>
#include <hip/hip_bf16.h>

#define Bb 2
#define HD 96
#define DI 192
#define LL 4096
#define Kd 4
#define Ns 16
#define Rr 6
#define SEG 256
#define SEGLEN 16
#define NBKCN (Bb*Kd*DI*Ns)   // 24576
#define LNEPS 1e-5f
#define RW 40                  // dblp row: 6 dt | 2 pad | 16 B | 16 C
#define LOG2E 1.44269504f

// fused: in_conv(96->96) + chanLN + in_proj(96->192)
// block = (ltile16, b), 192 thr; phase1 thread=(l=t&15, cg=t>>4: 12 x 8ch)
__global__ __launch_bounds__(192) void k_fused_in(const float* __restrict__ x,
    const float* __restrict__ w1, const float* __restrict__ g, const float* __restrict__ be,
    const float* __restrict__ w2, float* __restrict__ x1, float* __restrict__ hp) {
  __shared__ float xs[HD][17];
  __shared__ float t1[HD][17];
  __shared__ float red[2][16][12];
  int t = threadIdx.x;
  int l0 = blockIdx.x*16; int b = blockIdx.y;
  for (int idx=t; idx<HD*16; idx+=192) {
    int row = idx>>4, i = idx&15;
    xs[row][i] = x[((size_t)b*HD + row)*LL + l0 + i];
  }
  __syncthreads();
  int l = t & 15, cg = t >> 4;
  float acc8[8];
  #pragma unroll
  for (int q=0;q<8;q++) acc8[q]=0.f;
  for (int i=0;i<HD;i++) {
    float xv = xs[i][l];
    #pragma unroll
    for (int q=0;q<8;q++) acc8[q] += w1[(size_t)(cg*8+q)*HD + i]*xv;
  }
  float s=0.f, s2=0.f;
  #pragma unroll
  for (int q=0;q<8;q++) { s += acc8[q]; s2 += acc8[q]*acc8[q]; }
  red[0][l][cg]=s; red[1][l][cg]=s2;
  __syncthreads();
  float S=0.f, S2=0.f;
  #pragma unroll
  for (int q=0;q<12;q++) { S += red[0][l][q]; S2 += red[1][l][q]; }
  float mu = S*(1.f/HD);
  float var = S2*(1.f/HD) - mu*mu;
  float r = rsqrtf(var + LNEPS);
  #pragma unroll
  for (int q=0;q<8;q++) {
    int c = cg*8 + q;
    float v = (acc8[q]-mu)*r*g[c] + be[c];
    t1[c][l] = v;
    x1[((size_t)b*HD + c)*LL + l0 + l] = v;
  }
  __syncthreads();
  float acc16[16];
  #pragma unroll
  for (int q=0;q<16;q++) acc16[q]=0.f;
  for (int i=0;i<HD;i++) {
    float yv = t1[i][l];
    #pragma unroll
    for (int q=0;q<16;q++) acc16[q] += w2[(size_t)(cg*16+q)*HD + i]*yv;
  }
  #pragma unroll
  for (int q=0;q<16;q++)
    hp[((size_t)b*DI + cg*16+q)*LL + l0 + l] = acc16[q];
}

// depthwise 3x3 + bias + silu -> channel-last v_t[b][p][c]; 24-ch slabs
__global__ __launch_bounds__(192) void k_dwconv_silu_t(const float* __restrict__ hp,
    const float* __restrict__ wgt, const float* __restrict__ bias, float* __restrict__ v_t) {
  __shared__ float lds[24*65];
  int t = threadIdx.x;
  int w0 = t & 63, dg = t >> 6;
  int h = blockIdx.x, dq = blockIdx.y, b = blockIdx.z;
  for (int dd=0; dd<8; ++dd) {
    int dl = dg*8 + dd;
    int d = dq*24 + dl;
    const float* src = hp + ((size_t)b*DI + d)*LL;
    const float* wk = wgt + d*9;
    float acc = bias[d];
    #pragma unroll
    for (int dy=-1; dy<=1; dy++) {
      int hh = h+dy;
      if (hh < 0 || hh >= 64) continue;
      #pragma unroll
      for (int dx=-1; dx<=1; dx++) {
        int ww = w0+dx;
        if (ww < 0 || ww >= 64) continue;
        acc += wk[(dy+1)*3 + (dx+1)] * src[hh*64 + ww];
      }
    }
    lds[dl*65 + w0] = acc / (1.f + __expf(-acc));
  }
  __syncthreads();
  int hc = t % 24, ig = t / 24;
  if (ig < 8) {
    for (int ii=0; ii<8; ii++) {
      int i = ig*8 + ii;
      v_t[((size_t)b*LL + h*64 + i)*DI + dq*24 + hc] = lds[hc*65 + i];
    }
  }
}

// dblp[b][k][p][40] = W_k(38x192).v_row(p); padded layout 6|2|16|16
__global__ __launch_bounds__(256) void k_proj(const float* __restrict__ v_t,
    const float* __restrict__ xpw, float* __restrict__ dblp) {
  __shared__ float lds[32*196];
  int t = threadIdx.x;
  int pt = blockIdx.x, k = blockIdx.y, b = blockIdx.z;
  const float4* src = (const float4*)(v_t + ((size_t)b*LL + pt*32)*DI);
  for (int idx=t; idx<32*48; idx+=256) {
    int row = idx/48, q = idx - row*48;
    *((float4*)&lds[row*196 + 4*q]) = src[idx];
  }
  __syncthreads();
  int p = t & 31, dg = t >> 5;
  int d0 = (dg<6) ? dg*5 : 30 + (dg-6)*4;
  int nd = (dg<6) ? 5 : 4;
  float acc[5];
  #pragma unroll
  for (int q=0;q<5;q++) acc[q]=0.f;
  const float4* W4 = (const float4*)(xpw + (size_t)(k*38 + d0)*DI);
  const float4* row4 = (const float4*)(lds + p*196);
  for (int c4=0;c4<48;c4++) {
    float4 xv = row4[c4];
    #pragma unroll
    for (int dd=0;dd<5;dd++) {
      if (dd < nd) {
        float4 wv = W4[(size_t)dd*48 + c4];
        acc[dd] += xv.x*wv.x + xv.y*wv.y + xv.z*wv.z + xv.w*wv.w;
      }
    }
  }
  float* o = dblp + (((size_t)b*4 + k)*LL + pt*32 + p)*RW;
  for (int dd=0;dd<nd;dd++) {
    int d = d0 + dd;
    o[d + ((d>=6)?2:0)] = acc[dd];
  }
}

__device__ __forceinline__ void dir_map(int k, int s, int& pbase, int& pstr) {
  if (k==0)      { pbase = s*16;                          pstr = 1;   }
  else if (k==1) { pbase = (s&3)*1024 + (s>>2);           pstr = 64;  }
  else if (k==2) { pbase = 4095 - s*16;                   pstr = -1;  }
  else           { pbase = 4095 - (s&3)*1024 - (s>>2);    pstr = -64; }
}

__device__ __forceinline__ float softplus_f(float raw) {
  float e = __expf(raw);
  float l = __logf(1.f + e);
  return (raw > 20.f) ? raw : l;
}

// pass A: 2 segments per 384-thr block; u + dblp rows LDS-staged
__global__ __launch_bounds__(384) void k_scanA(const float* __restrict__ v_t,
    const float* __restrict__ dblp, const float* __restrict__ dtw,
    const float* __restrict__ dtb, const float* __restrict__ A_log,
    float* __restrict__ hend, float* __restrict__ sdt_o) {
  __shared__ float uld[2][SEGLEN][DI];
  __shared__ float rows[2][SEGLEN][24];
  int t = threadIdx.x;
  int sub = t/192, tl = t - sub*192;
  int s = blockIdx.x*2 + sub;
  int k = blockIdx.y, b = blockIdx.z;
  int bk = b*4 + k;
  int pbase, pstr; dir_map(k, s, pbase, pstr);
  for (int j=0;j<SEGLEN;j++)
    uld[sub][j][tl] = v_t[((size_t)b*LL + pbase + j*pstr)*DI + tl];
  if (tl < 96) {
    int r = tl/6, q = tl - r*6;
    const float4* src = (const float4*)(dblp + ((size_t)bk*LL + pbase + r*pstr)*RW);
    *((float4*)&rows[sub][r][4*q]) = src[q];
  }
  int c = tl;
  float w[6];
  {
    const float* wr = dtw + ((size_t)k*DI + c)*Rr;
    #pragma unroll
    for (int r=0;r<6;r++) w[r] = wr[r];
  }
  float bias = dtb[k*DI + c];
  float A2[16];
  {
    const float4* Ap = (const float4*)(A_log + ((size_t)k*DI + c)*Ns);
    #pragma unroll
    for (int q=0;q<4;q++) {
      float4 av = Ap[q];
      A2[4*q+0]=-__expf(av.x)*LOG2E; A2[4*q+1]=-__expf(av.y)*LOG2E;
      A2[4*q+2]=-__expf(av.z)*LOG2E; A2[4*q+3]=-__expf(av.w)*LOG2E;
    }
  }
  __syncthreads();
  float h[16];
  #pragma unroll
  for (int n=0;n<16;n++) h[n]=0.f;
  float sdt = 0.f;
  #pragma unroll 2
  for (int j=0;j<SEGLEN;j++) {
    const float* row = &rows[sub][j][0];
    float4 d0 = *((const float4*)row);
    float2 d1 = *((const float2*)(row+4));
    float raw = bias + w[0]*d0.x + w[1]*d0.y + w[2]*d0.z + w[3]*d0.w
              + w[4]*d1.x + w[5]*d1.y;
    float dt = softplus_f(raw);
    float du = dt * uld[sub][j][c];
    sdt += dt;
    const float4* Bv = (const float4*)(row+8);
    #pragma unroll
    for (int q=0;q<4;q++) {
      float4 bv = Bv[q];
      h[4*q+0] = h[4*q+0]*__builtin_amdgcn_exp2f(dt*A2[4*q+0]) + du*bv.x;
      h[4*q+1] = h[4*q+1]*__builtin_amdgcn_exp2f(dt*A2[4*q+1]) + du*bv.y;
      h[4*q+2] = h[4*q+2]*__builtin_amdgcn_exp2f(dt*A2[4*q+2]) + du*bv.z;
      h[4*q+3] = h[4*q+3]*__builtin_amdgcn_exp2f(dt*A2[4*q+3]) + du*bv.w;
    }
  }
  float* ho = hend + ((size_t)s*8 + bk)*(DI*Ns) + c;
  #pragma unroll
  for (int n=0;n<16;n++) ho[(size_t)n*DI] = h[n];
  sdt_o[((size_t)s*8 + bk)*DI + c] = sdt;
}

// fix-up: hend -> h_init in place; t = bk*3072 + n*192 + c
__global__ __launch_bounds__(256) void k_fix(float* __restrict__ hend,
    const float* __restrict__ sdt, const float* __restrict__ A_log) {
  int t = blockIdx.x*256 + threadIdx.x;
  int c = t % DI;
  int nn = (t / DI) & 15;
  int bk = t / (DI*Ns);
  int k = bk & 3;
  float A = -__expf(A_log[((size_t)k*DI + c)*Ns + nn]);
  float hi = 0.f;
  #pragma unroll 8
  for (int s=0; s<SEG; s++) {
    float he = hend[(size_t)s*NBKCN + t];
    float P  = __expf(A * sdt[(size_t)s*(8*DI) + bk*DI + c]);
    hend[(size_t)s*NBKCN + t] = hi;
    hi = he + P*hi;
  }
}

// pass B: rescan from h_init, emit y scattered to ORIGINAL positions
__global__ __launch_bounds__(384) void k_scanB(const float* __restrict__ v_t,
    const float* __restrict__ dblp, const float* __restrict__ dtw,
    const float* __restrict__ dtb, const float* __restrict__ A_log,
    const float* __restrict__ hinit, float* __restrict__ ym) {
  __shared__ float uld[2][SEGLEN][DI];
  __shared__ float rows[2][SEGLEN][RW];
  int t = threadIdx.x;
  int sub = t/192, tl = t - sub*192;
  int s = blockIdx.x*2 + sub;
  int k = blockIdx.y, b = blockIdx.z;
  int bk = b*4 + k;
  int pbase, pstr; dir_map(k, s, pbase, pstr);
  for (int j=0;j<SEGLEN;j++)
    uld[sub][j][tl] = v_t[((size_t)b*LL + pbase + j*pstr)*DI + tl];
  if (tl < 160) {
    int r = tl/10, q = tl - r*10;
    const float4* src = (const float4*)(dblp + ((size_t)bk*LL + pbase + r*pstr)*RW);
    *((float4*)&rows[sub][r][4*q]) = src[q];
  }
  int c = tl;
  float w[6];
  {
    const float* wr = dtw + ((size_t)k*DI + c)*Rr;
    #pragma unroll
    for (int r=0;r<6;r++) w[r] = wr[r];
  }
  float bias = dtb[k*DI + c];
  float A2[16];
  {
    const float4* Ap = (const float4*)(A_log + ((size_t)k*DI + c)*Ns);
    #pragma unroll
    for (int q=0;q<4;q++) {
      float4 av = Ap[q];
      A2[4*q+0]=-__expf(av.x)*LOG2E; A2[4*q+1]=-__expf(av.y)*LOG2E;
      A2[4*q+2]=-__expf(av.z)*LOG2E; A2[4*q+3]=-__expf(av.w)*LOG2E;
    }
  }
  float h[16];
  {
    const float* hi = hinit + ((size_t)s*8 + bk)*(DI*Ns) + c;
    #pragma unroll
    for (int n=0;n<16;n++) h[n] = hi[(size_t)n*DI];
  }
  __syncthreads();
  float* ymk = ym + ((size_t)(k*Bb + b)*LL)*DI;
  #pragma unroll 2
  for (int j=0;j<SEGLEN;j++) {
    const float* row = &rows[sub][j][0];
    float4 d0 = *((const float4*)row);
    float2 d1 = *((const float2*)(row+4));
    float raw = bias + w[0]*d0.x + w[1]*d0.y + w[2]*d0.z + w[3]*d0.w
              + w[4]*d1.x + w[5]*d1.y;
    float dt = softplus_f(raw);
    float du = dt * uld[sub][j][c];
    const float4* Bv = (const float4*)(row+8);
    const float4* Cv = (const float4*)(row+24);
    float y = 0.f;
    #pragma unroll
    for (int q=0;q<4;q++) {
      float4 bv = Bv[q];
      float4 cv = Cv[q];
      h[4*q+0] = h[4*q+0]*__builtin_amdgcn_exp2f(dt*A2[4*q+0]) + du*bv.x;
      h[4*q+1] = h[4*q+1]*__builtin_amdgcn_exp2f(dt*A2[4*q+1]) + du*bv.y;
      h[4*q+2] = h[4*q+2]*__builtin_amdgcn_exp2f(dt*A2[4*q+2]) + du*bv.z;
      h[4*q+3] = h[4*q+3]*__builtin_amdgcn_exp2f(dt*A2[4*q+3]) + du*bv.w;
      y += h[4*q+0]*cv.x + h[4*q+1]*cv.y + h[4*q+2]*cv.z + h[4*q+3]*cv.w;
    }
    int p = pbase + j*pstr;
    ymk[(size_t)p*DI + c] = y;
  }
}

// fused: merge 4 dirs + D-term + chanLN(192) + out_proj(192->96) + skip -> out
// block = (ltile16, b), 192 thr
#define MLT 16
__global__ __launch_bounds__(192) void k_merge_out(const float* __restrict__ ym,
    const float* __restrict__ v_t, const float* __restrict__ Ds,
    const float* __restrict__ g, const float* __restrict__ be,
    const float* __restrict__ w3, const float* __restrict__ x1,
    const float* __restrict__ ss, float* __restrict__ out) {
  __shared__ float tile[DI*(MLT+1)];
  __shared__ float red[2][MLT][4];
  int c = threadIdx.x;
  int b = blockIdx.y;
  int l0 = blockIdx.x*MLT;
  float sd = Ds[c] + Ds[DI+c] + Ds[2*DI+c] + Ds[3*DI+c];
  float gg = g[c], bb = be[c];
  int wv = c >> 6, ln = c & 63;
  float v[MLT];
  #pragma unroll
  for (int i=0;i<MLT;i++) {
    size_t row = ((size_t)b*LL + l0 + i)*DI + c;
    float vv = ym[row] + ym[(size_t)2*LL*DI + row]
             + ym[(size_t)4*LL*DI + row] + ym[(size_t)6*LL*DI + row]
             + v_t[row]*sd;
    v[i] = vv;
    float s = vv, s2 = vv*vv;
    #pragma unroll
    for (int d=1; d<64; d<<=1) { s += __shfl_xor(s,d); s2 += __shfl_xor(s2,d); }
    if (ln==0) { red[0][i][wv]=s; red[1][i][wv]=s2; }
  }
  __syncthreads();
  #pragma unroll
  for (int i=0;i<MLT;i++) {
    float S  = red[0][i][0]+red[0][i][1]+red[0][i][2];
    float S2 = red[1][i][0]+red[1][i][1]+red[1][i][2];
    float mu = S*(1.f/DI);
    float var = S2*(1.f/DI) - mu*mu;
    float r = rsqrtf(var + LNEPS);
    tile[c*(MLT+1) + i] = (v[i]-mu)*r*gg + bb;
  }
  __syncthreads();
  // phase2: out_proj; thread = (l=t&15, og=t>>4: 12 groups x 8 outputs)
  int l = threadIdx.x & 15, og = threadIdx.x >> 4;
  float acc8[8];
  #pragma unroll
  for (int q=0;q<8;q++) acc8[q]=0.f;
  for (int cc=0; cc<DI; cc++) {
    float yv = tile[cc*(MLT+1) + l];
    #pragma unroll
    for (int q=0;q<8;q++) acc8[q] += w3[(size_t)(og*8+q)*DI + cc]*yv;
  }
  float sc = ss[0];
  #pragma unroll
  for (int q=0;q<8;q++) {
    int o = og*8 + q;
    size_t oo = ((size_t)b*HD + o)*LL + l0 + l;
    out[oo] = acc8[q] + x1[oo]*sc;
  }
}

extern "C" void kernel_launch(void* const* d_in, const int* in_sizes, int n_in,
                              void* d_out, int out_size, void* d_ws, size_t ws_size,
                              hipStream_t stream) {
  const float* x         = (const float*)d_in[0];
  const float* in_conv_w = (const float*)d_in[1];
  const float* ln1_g     = (const float*)d_in[2];
  const float* ln1_b     = (const float*)d_in[3];
  const float* in_proj_w = (const float*)d_in[4];
  const float* dw_w      = (const float*)d_in[5];
  const float* dw_b      = (const float*)d_in[6];
  const float* x_proj_w  = (const float*)d_in[7];
  const float* dt_proj_w = (const float*)d_in[8];
  const float* dt_proj_b = (const float*)d_in[9];
  const float* A_log     = (const float*)d_in[10];
  const float* Ds        = (const float*)d_in[11];
  const float* onorm_g   = (const float*)d_in[12];
  const float* onorm_b   = (const float*)d_in[13];
  const float* out_proj_w= (const float*)d_in[14];
  const float* skip_s    = (const float*)d_in[15];
  float* out = (float*)d_out;

  float* ws   = (float*)d_ws;
  float* x1   = ws;                  //   786,432
  float* hp   = x1   + 786432;       // 1,572,864
  float* v_t  = hp   + 1572864;      // 1,572,864
  float* dblp = v_t  + 1572864;      // 1,310,720
  float* hend = dblp + 1310720;      // 6,291,456
  float* sdt  = hend + 6291456;      //   393,216
  float* ym   = sdt  + 393216;       // 6,291,456 (4 x [b][p][c])

  k_fused_in<<<dim3(LL/16, Bb), dim3(192), 0, stream>>>(x, in_conv_w, ln1_g, ln1_b, in_proj_w, x1, hp);
  k_dwconv_silu_t<<<dim3(64, 8, Bb), dim3(192), 0, stream>>>(hp, dw_w, dw_b, v_t);
  k_proj   <<<dim3(LL/32, Kd, Bb), dim3(256), 0, stream>>>(v_t, x_proj_w, dblp);
  k_scanA  <<<dim3(SEG/2, Kd, Bb), dim3(384), 0, stream>>>(v_t, dblp, dt_proj_w, dt_proj_b, A_log, hend, sdt);
  k_fix    <<<dim3(NBKCN/256), dim3(256), 0, stream>>>(hend, sdt, A_log);
  k_scanB  <<<dim3(SEG/2, Kd, Bb), dim3(384), 0, stream>>>(v_t, dblp, dt_proj_w, dt_proj_b, A_log, hend, ym);
  k_merge_out<<<dim3(LL/MLT, Bb), dim3(192), 0, stream>>>(ym, v_t, Ds, onorm_g, onorm_b, out_proj_w, x1, skip_s, out);
}

// Round 10
// 282.484 us; speedup vs baseline: 2.2686x; 1.0162x over previous
//
#include <hip/hip_runtime.h>
#include <hip/hip_bf16.h>

#define Bb 2
#define HD 96
#define DI 192
#define LL 4096
#define Kd 4
#define Ns 16
#define Rr 6
#define SEG 256
#define SEGLEN 16
#define NBKCN (Bb*Kd*DI*Ns)   // 24576
#define LNEPS 1e-5f
#define RW 40                  // dblp row: 6 dt | 2 pad | 16 B | 16 C
#define LOG2E 1.44269504f

// fused: in_conv(96->96) + chanLN + in_proj(96->192)
// block=(ltile16,b), 384 thr = (l=t&15, cg=t>>4 in 0..23); f4 dots from [l][c] LDS tiles
__global__ __launch_bounds__(384) void k_fused_in(const float* __restrict__ x,
    const float* __restrict__ w1, const float* __restrict__ g, const float* __restrict__ be,
    const float* __restrict__ w2, float* __restrict__ x1, float* __restrict__ hp) {
  __shared__ float xs[16][100];
  __shared__ float t1[16][100];
  __shared__ float red[2][16][24];
  int t = threadIdx.x;
  int l0 = blockIdx.x*16; int b = blockIdx.y;
  for (int idx=t; idx<HD*16; idx+=384) {
    int c = idx>>4, i = idx&15;
    xs[i][c] = x[((size_t)b*HD + c)*LL + l0 + i];
  }
  __syncthreads();
  int l = t & 15, cg = t >> 4;
  // phase1: 4 out-ch per thread, f4 dot over 96
  float a0=0.f,a1=0.f,a2=0.f,a3=0.f;
  {
    const float4* xr = (const float4*)&xs[l][0];
    const float4* wr0 = (const float4*)(w1 + (size_t)(cg*4+0)*HD);
    const float4* wr1 = (const float4*)(w1 + (size_t)(cg*4+1)*HD);
    const float4* wr2 = (const float4*)(w1 + (size_t)(cg*4+2)*HD);
    const float4* wr3 = (const float4*)(w1 + (size_t)(cg*4+3)*HD);
    #pragma unroll 6
    for (int j=0;j<24;j++) {
      float4 xv = xr[j];
      float4 v0 = wr0[j], v1 = wr1[j], v2 = wr2[j], v3 = wr3[j];
      a0 += xv.x*v0.x + xv.y*v0.y + xv.z*v0.z + xv.w*v0.w;
      a1 += xv.x*v1.x + xv.y*v1.y + xv.z*v1.z + xv.w*v1.w;
      a2 += xv.x*v2.x + xv.y*v2.y + xv.z*v2.z + xv.w*v2.w;
      a3 += xv.x*v3.x + xv.y*v3.y + xv.z*v3.z + xv.w*v3.w;
    }
  }
  float s = a0+a1+a2+a3;
  float s2 = a0*a0+a1*a1+a2*a2+a3*a3;
  red[0][l][cg]=s; red[1][l][cg]=s2;
  __syncthreads();
  float S=0.f, S2=0.f;
  #pragma unroll
  for (int q=0;q<24;q++) { S += red[0][l][q]; S2 += red[1][l][q]; }
  float mu = S*(1.f/HD);
  float var = S2*(1.f/HD) - mu*mu;
  float r = rsqrtf(var + LNEPS);
  {
    int c0 = cg*4;
    float v0 = (a0-mu)*r*g[c0+0] + be[c0+0];
    float v1 = (a1-mu)*r*g[c0+1] + be[c0+1];
    float v2 = (a2-mu)*r*g[c0+2] + be[c0+2];
    float v3 = (a3-mu)*r*g[c0+3] + be[c0+3];
    t1[l][c0+0]=v0; t1[l][c0+1]=v1; t1[l][c0+2]=v2; t1[l][c0+3]=v3;
    size_t ob = ((size_t)b*HD + c0)*LL + l0 + l;
    x1[ob]=v0; x1[ob+LL]=v1; x1[ob+2*(size_t)LL]=v2; x1[ob+3*(size_t)LL]=v3;
  }
  __syncthreads();
  // phase2: 8 out-ch per thread, f4 dot over 96
  float acc[8];
  #pragma unroll
  for (int q=0;q<8;q++) acc[q]=0.f;
  {
    const float4* yr = (const float4*)&t1[l][0];
    #pragma unroll 4
    for (int j=0;j<24;j++) {
      float4 yv = yr[j];
      #pragma unroll
      for (int q=0;q<8;q++) {
        float4 wv = ((const float4*)(w2 + (size_t)(cg*8+q)*HD))[j];
        acc[q] += yv.x*wv.x + yv.y*wv.y + yv.z*wv.z + yv.w*wv.w;
      }
    }
  }
  #pragma unroll
  for (int q=0;q<8;q++)
    hp[((size_t)b*DI + cg*8+q)*LL + l0 + l] = acc[q];
}

// depthwise 3x3 + bias + silu -> channel-last v_t[b][p][c]; 24-ch slabs
__global__ __launch_bounds__(192) void k_dwconv_silu_t(const float* __restrict__ hp,
    const float* __restrict__ wgt, const float* __restrict__ bias, float* __restrict__ v_t) {
  __shared__ float lds[24*65];
  int t = threadIdx.x;
  int w0 = t & 63, dg = t >> 6;
  int h = blockIdx.x, dq = blockIdx.y, b = blockIdx.z;
  for (int dd=0; dd<8; ++dd) {
    int dl = dg*8 + dd;
    int d = dq*24 + dl;
    const float* src = hp + ((size_t)b*DI + d)*LL;
    const float* wk = wgt + d*9;
    float acc = bias[d];
    #pragma unroll
    for (int dy=-1; dy<=1; dy++) {
      int hh = h+dy;
      if (hh < 0 || hh >= 64) continue;
      #pragma unroll
      for (int dx=-1; dx<=1; dx++) {
        int ww = w0+dx;
        if (ww < 0 || ww >= 64) continue;
        acc += wk[(dy+1)*3 + (dx+1)] * src[hh*64 + ww];
      }
    }
    lds[dl*65 + w0] = acc / (1.f + __expf(-acc));
  }
  __syncthreads();
  int hc = t % 24, ig = t / 24;
  if (ig < 8) {
    for (int ii=0; ii<8; ii++) {
      int i = ig*8 + ii;
      v_t[((size_t)b*LL + h*64 + i)*DI + dq*24 + hc] = lds[hc*65 + i];
    }
  }
}

// dblp[b][k][p][40] = W_k(38x192).v_row(p); 512 thr = (p=t&63, dg=t>>6 wave-uniform)
__global__ __launch_bounds__(512) void k_proj(const float* __restrict__ v_t,
    const float* __restrict__ xpw, float* __restrict__ dblp) {
  __shared__ float lds[64*196];
  int t = threadIdx.x;
  int pt = blockIdx.x, k = blockIdx.y, b = blockIdx.z;
  const float4* src = (const float4*)(v_t + ((size_t)b*LL + pt*64)*DI);
  for (int idx=t; idx<64*48; idx+=512) {
    int p = idx/48, q = idx - p*48;
    *((float4*)&lds[p*196 + 4*q]) = src[idx];
  }
  __syncthreads();
  int p = t & 63, dg = t >> 6;           // dg wave-uniform
  int d0 = (dg<6) ? dg*5 : 30 + (dg-6)*4;
  int nd = (dg<6) ? 5 : 4;
  float acc[5];
  #pragma unroll
  for (int q=0;q<5;q++) acc[q]=0.f;
  const float4* W4 = (const float4*)(xpw + (size_t)(k*38 + d0)*DI);
  const float4* row4 = (const float4*)(lds + p*196);
  for (int c4=0;c4<48;c4++) {
    float4 xv = row4[c4];
    #pragma unroll
    for (int dd=0;dd<5;dd++) {
      if (dd < nd) {
        float4 wv = W4[(size_t)dd*48 + c4];
        acc[dd] += xv.x*wv.x + xv.y*wv.y + xv.z*wv.z + xv.w*wv.w;
      }
    }
  }
  float* o = dblp + (((size_t)b*4 + k)*LL + pt*64 + p)*RW;
  for (int dd=0;dd<nd;dd++) {
    int d = d0 + dd;
    o[d + ((d>=6)?2:0)] = acc[dd];
  }
}

__device__ __forceinline__ void dir_map(int k, int s, int& pbase, int& pstr) {
  if (k==0)      { pbase = s*16;                          pstr = 1;   }
  else if (k==1) { pbase = (s&3)*1024 + (s>>2);           pstr = 64;  }
  else if (k==2) { pbase = 4095 - s*16;                   pstr = -1;  }
  else           { pbase = 4095 - (s&3)*1024 - (s>>2);    pstr = -64; }
}

__device__ __forceinline__ float softplus_f(float raw) {
  float e = __expf(raw);
  float l = __logf(1.f + e);
  return (raw > 20.f) ? raw : l;
}

// pass A: 2 segments per 384-thr block; u + dblp rows LDS-staged
__global__ __launch_bounds__(384) void k_scanA(const float* __restrict__ v_t,
    const float* __restrict__ dblp, const float* __restrict__ dtw,
    const float* __restrict__ dtb, const float* __restrict__ A_log,
    float* __restrict__ hend, float* __restrict__ sdt_o) {
  __shared__ float uld[2][SEGLEN][DI];
  __shared__ float rows[2][SEGLEN][24];
  int t = threadIdx.x;
  int sub = t/192, tl = t - sub*192;
  int s = blockIdx.x*2 + sub;
  int k = blockIdx.y, b = blockIdx.z;
  int bk = b*4 + k;
  int pbase, pstr; dir_map(k, s, pbase, pstr);
  for (int j=0;j<SEGLEN;j++)
    uld[sub][j][tl] = v_t[((size_t)b*LL + pbase + j*pstr)*DI + tl];
  if (tl < 96) {
    int r = tl/6, q = tl - r*6;
    const float4* src = (const float4*)(dblp + ((size_t)bk*LL + pbase + r*pstr)*RW);
    *((float4*)&rows[sub][r][4*q]) = src[q];
  }
  int c = tl;
  float w[6];
  {
    const float* wr = dtw + ((size_t)k*DI + c)*Rr;
    #pragma unroll
    for (int r=0;r<6;r++) w[r] = wr[r];
  }
  float bias = dtb[k*DI + c];
  float A2[16];
  {
    const float4* Ap = (const float4*)(A_log + ((size_t)k*DI + c)*Ns);
    #pragma unroll
    for (int q=0;q<4;q++) {
      float4 av = Ap[q];
      A2[4*q+0]=-__expf(av.x)*LOG2E; A2[4*q+1]=-__expf(av.y)*LOG2E;
      A2[4*q+2]=-__expf(av.z)*LOG2E; A2[4*q+3]=-__expf(av.w)*LOG2E;
    }
  }
  __syncthreads();
  float h[16];
  #pragma unroll
  for (int n=0;n<16;n++) h[n]=0.f;
  float sdt = 0.f;
  #pragma unroll 2
  for (int j=0;j<SEGLEN;j++) {
    const float* row = &rows[sub][j][0];
    float4 d0 = *((const float4*)row);
    float2 d1 = *((const float2*)(row+4));
    float raw = bias + w[0]*d0.x + w[1]*d0.y + w[2]*d0.z + w[3]*d0.w
              + w[4]*d1.x + w[5]*d1.y;
    float dt = softplus_f(raw);
    float du = dt * uld[sub][j][c];
    sdt += dt;
    const float4* Bv = (const float4*)(row+8);
    #pragma unroll
    for (int q=0;q<4;q++) {
      float4 bv = Bv[q];
      h[4*q+0] = h[4*q+0]*__builtin_amdgcn_exp2f(dt*A2[4*q+0]) + du*bv.x;
      h[4*q+1] = h[4*q+1]*__builtin_amdgcn_exp2f(dt*A2[4*q+1]) + du*bv.y;
      h[4*q+2] = h[4*q+2]*__builtin_amdgcn_exp2f(dt*A2[4*q+2]) + du*bv.z;
      h[4*q+3] = h[4*q+3]*__builtin_amdgcn_exp2f(dt*A2[4*q+3]) + du*bv.w;
    }
  }
  float* ho = hend + ((size_t)s*8 + bk)*(DI*Ns) + c;
  #pragma unroll
  for (int n=0;n<16;n++) ho[(size_t)n*DI] = h[n];
  sdt_o[((size_t)s*8 + bk)*DI + c] = sdt;
}

// fix-up: hend -> h_init in place; t = bk*3072 + n*192 + c
__global__ __launch_bounds__(256) void k_fix(float* __restrict__ hend,
    const float* __restrict__ sdt, const float* __restrict__ A_log) {
  int t = blockIdx.x*256 + threadIdx.x;
  int c = t % DI;
  int nn = (t / DI) & 15;
  int bk = t / (DI*Ns);
  int k = bk & 3;
  float A = -__expf(A_log[((size_t)k*DI + c)*Ns + nn]);
  float hi = 0.f;
  #pragma unroll 8
  for (int s=0; s<SEG; s++) {
    float he = hend[(size_t)s*NBKCN + t];
    float P  = __expf(A * sdt[(size_t)s*(8*DI) + bk*DI + c]);
    hend[(size_t)s*NBKCN + t] = hi;
    hi = he + P*hi;
  }
}

// pass B: rescan from h_init, emit y scattered to ORIGINAL positions
__global__ __launch_bounds__(384) void k_scanB(const float* __restrict__ v_t,
    const float* __restrict__ dblp, const float* __restrict__ dtw,
    const float* __restrict__ dtb, const float* __restrict__ A_log,
    const float* __restrict__ hinit, float* __restrict__ ym) {
  __shared__ float uld[2][SEGLEN][DI];
  __shared__ float rows[2][SEGLEN][RW];
  int t = threadIdx.x;
  int sub = t/192, tl = t - sub*192;
  int s = blockIdx.x*2 + sub;
  int k = blockIdx.y, b = blockIdx.z;
  int bk = b*4 + k;
  int pbase, pstr; dir_map(k, s, pbase, pstr);
  for (int j=0;j<SEGLEN;j++)
    uld[sub][j][tl] = v_t[((size_t)b*LL + pbase + j*pstr)*DI + tl];
  if (tl < 160) {
    int r = tl/10, q = tl - r*10;
    const float4* src = (const float4*)(dblp + ((size_t)bk*LL + pbase + r*pstr)*RW);
    *((float4*)&rows[sub][r][4*q]) = src[q];
  }
  int c = tl;
  float w[6];
  {
    const float* wr = dtw + ((size_t)k*DI + c)*Rr;
    #pragma unroll
    for (int r=0;r<6;r++) w[r] = wr[r];
  }
  float bias = dtb[k*DI + c];
  float A2[16];
  {
    const float4* Ap = (const float4*)(A_log + ((size_t)k*DI + c)*Ns);
    #pragma unroll
    for (int q=0;q<4;q++) {
      float4 av = Ap[q];
      A2[4*q+0]=-__expf(av.x)*LOG2E; A2[4*q+1]=-__expf(av.y)*LOG2E;
      A2[4*q+2]=-__expf(av.z)*LOG2E; A2[4*q+3]=-__expf(av.w)*LOG2E;
    }
  }
  float h[16];
  {
    const float* hi = hinit + ((size_t)s*8 + bk)*(DI*Ns) + c;
    #pragma unroll
    for (int n=0;n<16;n++) h[n] = hi[(size_t)n*DI];
  }
  __syncthreads();
  float* ymk = ym + ((size_t)(k*Bb + b)*LL)*DI;
  #pragma unroll 2
  for (int j=0;j<SEGLEN;j++) {
    const float* row = &rows[sub][j][0];
    float4 d0 = *((const float4*)row);
    float2 d1 = *((const float2*)(row+4));
    float raw = bias + w[0]*d0.x + w[1]*d0.y + w[2]*d0.z + w[3]*d0.w
              + w[4]*d1.x + w[5]*d1.y;
    float dt = softplus_f(raw);
    float du = dt * uld[sub][j][c];
    const float4* Bv = (const float4*)(row+8);
    const float4* Cv = (const float4*)(row+24);
    float y = 0.f;
    #pragma unroll
    for (int q=0;q<4;q++) {
      float4 bv = Bv[q];
      float4 cv = Cv[q];
      h[4*q+0] = h[4*q+0]*__builtin_amdgcn_exp2f(dt*A2[4*q+0]) + du*bv.x;
      h[4*q+1] = h[4*q+1]*__builtin_amdgcn_exp2f(dt*A2[4*q+1]) + du*bv.y;
      h[4*q+2] = h[4*q+2]*__builtin_amdgcn_exp2f(dt*A2[4*q+2]) + du*bv.z;
      h[4*q+3] = h[4*q+3]*__builtin_amdgcn_exp2f(dt*A2[4*q+3]) + du*bv.w;
      y += h[4*q+0]*cv.x + h[4*q+1]*cv.y + h[4*q+2]*cv.z + h[4*q+3]*cv.w;
    }
    int p = pbase + j*pstr;
    ymk[(size_t)p*DI + c] = y;
  }
}

// fused: merge 4 dirs + D + chanLN(192) + out_proj + skip -> out
// block=(ltile16,b), 384 thr: phase1 (c=t%192, pp=t/192), phase2 (l=t&15, og=t>>4)
__global__ __launch_bounds__(384) void k_merge_out(const float* __restrict__ ym,
    const float* __restrict__ v_t, const float* __restrict__ Ds,
    const float* __restrict__ g, const float* __restrict__ be,
    const float* __restrict__ w3, const float* __restrict__ x1,
    const float* __restrict__ ss, float* __restrict__ out) {
  __shared__ float tile2[16*196];
  __shared__ float red[2][16][6];
  int t = threadIdx.x;
  int b = blockIdx.y;
  int l0 = blockIdx.x*16;
  int pp = t / 192, c = t - pp*192;
  int wv = t >> 6;               // global wave id 0..5
  int ln = t & 63;
  float sd = Ds[c] + Ds[DI+c] + Ds[2*DI+c] + Ds[3*DI+c];
  float gg = g[c], bb = be[c];
  float v[8];
  #pragma unroll
  for (int j=0;j<8;j++) {
    int i = 2*j + pp;
    size_t row = ((size_t)b*LL + l0 + i)*DI + c;
    float vv = ym[row] + ym[(size_t)2*LL*DI + row]
             + ym[(size_t)4*LL*DI + row] + ym[(size_t)6*LL*DI + row]
             + v_t[row]*sd;
    v[j] = vv;
    float s = vv, s2 = vv*vv;
    #pragma unroll
    for (int d=1; d<64; d<<=1) { s += __shfl_xor(s,d); s2 += __shfl_xor(s2,d); }
    if (ln==0) { red[0][i][wv]=s; red[1][i][wv]=s2; }
  }
  __syncthreads();
  #pragma unroll
  for (int j=0;j<8;j++) {
    int i = 2*j + pp;
    int w0i = pp*3;
    float S  = red[0][i][w0i]+red[0][i][w0i+1]+red[0][i][w0i+2];
    float S2 = red[1][i][w0i]+red[1][i][w0i+1]+red[1][i][w0i+2];
    float mu = S*(1.f/DI);
    float var = S2*(1.f/DI) - mu*mu;
    float r = rsqrtf(var + LNEPS);
    tile2[i*196 + c] = (v[j]-mu)*r*gg + bb;
  }
  __syncthreads();
  // phase2: out_proj, 4 outputs per thread via f4 dots
  int l = t & 15, og = t >> 4;   // og 0..23
  float a0=0.f,a1=0.f,a2=0.f,a3=0.f;
  {
    const float4* yr = (const float4*)&tile2[l*196];
    const float4* wr0 = (const float4*)(w3 + (size_t)(og*4+0)*DI);
    const float4* wr1 = (const float4*)(w3 + (size_t)(og*4+1)*DI);
    const float4* wr2 = (const float4*)(w3 + (size_t)(og*4+2)*DI);
    const float4* wr3 = (const float4*)(w3 + (size_t)(og*4+3)*DI);
    #pragma unroll 6
    for (int j=0;j<48;j++) {
      float4 yv = yr[j];
      float4 v0 = wr0[j], v1 = wr1[j], v2 = wr2[j], v3 = wr3[j];
      a0 += yv.x*v0.x + yv.y*v0.y + yv.z*v0.z + yv.w*v0.w;
      a1 += yv.x*v1.x + yv.y*v1.y + yv.z*v1.z + yv.w*v1.w;
      a2 += yv.x*v2.x + yv.y*v2.y + yv.z*v2.z + yv.w*v2.w;
      a3 += yv.x*v3.x + yv.y*v3.y + yv.z*v3.z + yv.w*v3.w;
    }
  }
  float sc = ss[0];
  int o0 = og*4;
  size_t ob = ((size_t)b*HD + o0)*LL + l0 + l;
  out[ob]            = a0 + x1[ob]*sc;
  out[ob+LL]         = a1 + x1[ob+LL]*sc;
  out[ob+2*(size_t)LL] = a2 + x1[ob+2*(size_t)LL]*sc;
  out[ob+3*(size_t)LL] = a3 + x1[ob+3*(size_t)LL]*sc;
}

extern "C" void kernel_launch(void* const* d_in, const int* in_sizes, int n_in,
                              void* d_out, int out_size, void* d_ws, size_t ws_size,
                              hipStream_t stream) {
  const float* x         = (const float*)d_in[0];
  const float* in_conv_w = (const float*)d_in[1];
  const float* ln1_g     = (const float*)d_in[2];
  const float* ln1_b     = (const float*)d_in[3];
  const float* in_proj_w = (const float*)d_in[4];
  const float* dw_w      = (const float*)d_in[5];
  const float* dw_b      = (const float*)d_in[6];
  const float* x_proj_w  = (const float*)d_in[7];
  const float* dt_proj_w = (const float*)d_in[8];
  const float* dt_proj_b = (const float*)d_in[9];
  const float* A_log     = (const float*)d_in[10];
  const float* Ds        = (const float*)d_in[11];
  const float* onorm_g   = (const float*)d_in[12];
  const float* onorm_b   = (const float*)d_in[13];
  const float* out_proj_w= (const float*)d_in[14];
  const float* skip_s    = (const float*)d_in[15];
  float* out = (float*)d_out;

  float* ws   = (float*)d_ws;
  float* x1   = ws;                  //   786,432
  float* hp   = x1   + 786432;       // 1,572,864
  float* v_t  = hp   + 1572864;      // 1,572,864
  float* dblp = v_t  + 1572864;      // 1,310,720
  float* hend = dblp + 1310720;      // 6,291,456
  float* sdt  = hend + 6291456;      //   393,216
  float* ym   = sdt  + 393216;       // 6,291,456 (4 x [b][p][c])

  k_fused_in<<<dim3(LL/16, Bb), dim3(384), 0, stream>>>(x, in_conv_w, ln1_g, ln1_b, in_proj_w, x1, hp);
  k_dwconv_silu_t<<<dim3(64, 8, Bb), dim3(192), 0, stream>>>(hp, dw_w, dw_b, v_t);
  k_proj   <<<dim3(LL/64, Kd, Bb), dim3(512), 0, stream>>>(v_t, x_proj_w, dblp);
  k_scanA  <<<dim3(SEG/2, Kd, Bb), dim3(384), 0, stream>>>(v_t, dblp, dt_proj_w, dt_proj_b, A_log, hend, sdt);
  k_fix    <<<dim3(NBKCN/256), dim3(256), 0, stream>>>(hend, sdt, A_log);
  k_scanB  <<<dim3(SEG/2, Kd, Bb), dim3(384), 0, stream>>>(v_t, dblp, dt_proj_w, dt_proj_b, A_log, hend, ym);
  k_merge_out<<<dim3(LL/16, Bb), dim3(384), 0, stream>>>(ym, v_t, Ds, onorm_g, onorm_b, out_proj_w, x1, skip_s, out);
}

// Round 12
// 278.047 us; speedup vs baseline: 2.3048x; 1.0160x over previous
//
#include <hip/hip_runtime.h>
#include <hip/hip_bf16.h>

#define Bb 2
#define HD 96
#define DI 192
#define LL 4096
#define Kd 4
#define Ns 16
#define Rr 6
#define SEG 256
#define SEGLEN 16
#define NBKCN (Bb*Kd*DI*Ns)   // 24576
#define LNEPS 1e-5f
#define RW 40                  // dblp row: 6 dt | 2 pad | 16 B | 16 C
#define LOG2E 1.44269504f

// fused: in_conv(96->96) + chanLN + in_proj(96->192)
__global__ __launch_bounds__(384) void k_fused_in(const float* __restrict__ x,
    const float* __restrict__ w1, const float* __restrict__ g, const float* __restrict__ be,
    const float* __restrict__ w2, float* __restrict__ x1, float* __restrict__ hp) {
  __shared__ float xs[16][100];
  __shared__ float t1[16][100];
  __shared__ float red[2][16][24];
  int t = threadIdx.x;
  int l0 = blockIdx.x*16; int b = blockIdx.y;
  for (int idx=t; idx<HD*16; idx+=384) {
    int c = idx>>4, i = idx&15;
    xs[i][c] = x[((size_t)b*HD + c)*LL + l0 + i];
  }
  __syncthreads();
  int l = t & 15, cg = t >> 4;
  float a0=0.f,a1=0.f,a2=0.f,a3=0.f;
  {
    const float4* xr = (const float4*)&xs[l][0];
    const float4* wr0 = (const float4*)(w1 + (size_t)(cg*4+0)*HD);
    const float4* wr1 = (const float4*)(w1 + (size_t)(cg*4+1)*HD);
    const float4* wr2 = (const float4*)(w1 + (size_t)(cg*4+2)*HD);
    const float4* wr3 = (const float4*)(w1 + (size_t)(cg*4+3)*HD);
    #pragma unroll 6
    for (int j=0;j<24;j++) {
      float4 xv = xr[j];
      float4 v0 = wr0[j], v1 = wr1[j], v2 = wr2[j], v3 = wr3[j];
      a0 += xv.x*v0.x + xv.y*v0.y + xv.z*v0.z + xv.w*v0.w;
      a1 += xv.x*v1.x + xv.y*v1.y + xv.z*v1.z + xv.w*v1.w;
      a2 += xv.x*v2.x + xv.y*v2.y + xv.z*v2.z + xv.w*v2.w;
      a3 += xv.x*v3.x + xv.y*v3.y + xv.z*v3.z + xv.w*v3.w;
    }
  }
  float s = a0+a1+a2+a3;
  float s2 = a0*a0+a1*a1+a2*a2+a3*a3;
  red[0][l][cg]=s; red[1][l][cg]=s2;
  __syncthreads();
  float S=0.f, S2=0.f;
  #pragma unroll
  for (int q=0;q<24;q++) { S += red[0][l][q]; S2 += red[1][l][q]; }
  float mu = S*(1.f/HD);
  float var = S2*(1.f/HD) - mu*mu;
  float r = rsqrtf(var + LNEPS);
  {
    int c0 = cg*4;
    float v0 = (a0-mu)*r*g[c0+0] + be[c0+0];
    float v1 = (a1-mu)*r*g[c0+1] + be[c0+1];
    float v2 = (a2-mu)*r*g[c0+2] + be[c0+2];
    float v3 = (a3-mu)*r*g[c0+3] + be[c0+3];
    t1[l][c0+0]=v0; t1[l][c0+1]=v1; t1[l][c0+2]=v2; t1[l][c0+3]=v3;
    size_t ob = ((size_t)b*HD + c0)*LL + l0 + l;
    x1[ob]=v0; x1[ob+LL]=v1; x1[ob+2*(size_t)LL]=v2; x1[ob+3*(size_t)LL]=v3;
  }
  __syncthreads();
  float acc[8];
  #pragma unroll
  for (int q=0;q<8;q++) acc[q]=0.f;
  {
    const float4* yr = (const float4*)&t1[l][0];
    #pragma unroll 4
    for (int j=0;j<24;j++) {
      float4 yv = yr[j];
      #pragma unroll
      for (int q=0;q<8;q++) {
        float4 wv = ((const float4*)(w2 + (size_t)(cg*8+q)*HD))[j];
        acc[q] += yv.x*wv.x + yv.y*wv.y + yv.z*wv.z + yv.w*wv.w;
      }
    }
  }
  #pragma unroll
  for (int q=0;q<8;q++)
    hp[((size_t)b*DI + cg*8+q)*LL + l0 + l] = acc[q];
}

// depthwise 3x3 + bias + silu -> channel-last v_t[b][p][c]; 24-ch slabs
__global__ __launch_bounds__(192) void k_dwconv_silu_t(const float* __restrict__ hp,
    const float* __restrict__ wgt, const float* __restrict__ bias, float* __restrict__ v_t) {
  __shared__ float lds[24*65];
  int t = threadIdx.x;
  int w0 = t & 63, dg = t >> 6;
  int h = blockIdx.x, dq = blockIdx.y, b = blockIdx.z;
  for (int dd=0; dd<8; ++dd) {
    int dl = dg*8 + dd;
    int d = dq*24 + dl;
    const float* src = hp + ((size_t)b*DI + d)*LL;
    const float* wk = wgt + d*9;
    float acc = bias[d];
    #pragma unroll
    for (int dy=-1; dy<=1; dy++) {
      int hh = h+dy;
      if (hh < 0 || hh >= 64) continue;
      #pragma unroll
      for (int dx=-1; dx<=1; dx++) {
        int ww = w0+dx;
        if (ww < 0 || ww >= 64) continue;
        acc += wk[(dy+1)*3 + (dx+1)] * src[hh*64 + ww];
      }
    }
    lds[dl*65 + w0] = acc / (1.f + __expf(-acc));
  }
  __syncthreads();
  int hc = t % 24, ig = t / 24;
  if (ig < 8) {
    for (int ii=0; ii<8; ii++) {
      int i = ig*8 + ii;
      v_t[((size_t)b*LL + h*64 + i)*DI + dq*24 + hc] = lds[hc*65 + i];
    }
  }
}

// dblp[b][k][p][40] = W_k(38x192).v_row(p); 512 thr = (p=t&63, dg=t>>6 wave-uniform)
__global__ __launch_bounds__(512) void k_proj(const float* __restrict__ v_t,
    const float* __restrict__ xpw, float* __restrict__ dblp) {
  __shared__ float lds[64*196];
  int t = threadIdx.x;
  int pt = blockIdx.x, k = blockIdx.y, b = blockIdx.z;
  const float4* src = (const float4*)(v_t + ((size_t)b*LL + pt*64)*DI);
  for (int idx=t; idx<64*48; idx+=512) {
    int p = idx/48, q = idx - p*48;
    *((float4*)&lds[p*196 + 4*q]) = src[idx];
  }
  __syncthreads();
  int p = t & 63, dg = t >> 6;
  int d0 = (dg<6) ? dg*5 : 30 + (dg-6)*4;
  int nd = (dg<6) ? 5 : 4;
  float acc[5];
  #pragma unroll
  for (int q=0;q<5;q++) acc[q]=0.f;
  const float4* W4 = (const float4*)(xpw + (size_t)(k*38 + d0)*DI);
  const float4* row4 = (const float4*)(lds + p*196);
  for (int c4=0;c4<48;c4++) {
    float4 xv = row4[c4];
    #pragma unroll
    for (int dd=0;dd<5;dd++) {
      if (dd < nd) {
        float4 wv = W4[(size_t)dd*48 + c4];
        acc[dd] += xv.x*wv.x + xv.y*wv.y + xv.z*wv.z + xv.w*wv.w;
      }
    }
  }
  float* o = dblp + (((size_t)b*4 + k)*LL + pt*64 + p)*RW;
  for (int dd=0;dd<nd;dd++) {
    int d = d0 + dd;
    o[d + ((d>=6)?2:0)] = acc[dd];
  }
}

__device__ __forceinline__ void dir_map(int k, int s, int& pbase, int& pstr) {
  if (k==0)      { pbase = s*16;                          pstr = 1;   }
  else if (k==1) { pbase = (s&3)*1024 + (s>>2);           pstr = 64;  }
  else if (k==2) { pbase = 4095 - s*16;                   pstr = -1;  }
  else           { pbase = 4095 - (s&3)*1024 - (s>>2);    pstr = -64; }
}

__device__ __forceinline__ float softplus_f(float raw) {
  float e = __expf(raw);
  float l = __logf(1.f + e);
  return (raw > 20.f) ? raw : l;
}

// pass A: 2 segments per 384-thr block; f4 staging; dt/du precomputed (trans off h-chain)
__global__ __launch_bounds__(384) void k_scanA(const float* __restrict__ v_t,
    const float* __restrict__ dblp, const float* __restrict__ dtw,
    const float* __restrict__ dtb, const float* __restrict__ A_log,
    float* __restrict__ hend, float* __restrict__ sdt_o) {
  __shared__ float uld[2][SEGLEN][DI];
  __shared__ float rows[2][SEGLEN][24];
  int t = threadIdx.x;
  int sub = t/192, tl = t - sub*192;
  int s = blockIdx.x*2 + sub;
  int k = blockIdx.y, b = blockIdx.z;
  int bk = b*4 + k;
  int pbase, pstr; dir_map(k, s, pbase, pstr);
  // stage u as f4: 16 rows x 48 f4 = 768 f4 per segment
  #pragma unroll
  for (int i=0;i<4;i++) {
    int idx = tl + i*192;
    int row = idx/48, q = idx - row*48;
    int p = pbase + row*pstr;
    const float4* src = (const float4*)(v_t + ((size_t)b*LL + p)*DI) + q;
    *((float4*)&uld[sub][row][4*q]) = *src;
  }
  if (tl < 96) {
    int r = tl/6, q = tl - r*6;
    const float4* src = (const float4*)(dblp + ((size_t)bk*LL + pbase + r*pstr)*RW);
    *((float4*)&rows[sub][r][4*q]) = src[q];
  }
  int c = tl;
  float w[6];
  {
    const float* wr = dtw + ((size_t)k*DI + c)*Rr;
    #pragma unroll
    for (int r=0;r<6;r++) w[r] = wr[r];
  }
  float bias = dtb[k*DI + c];
  float A2[16];
  {
    const float4* Ap = (const float4*)(A_log + ((size_t)k*DI + c)*Ns);
    #pragma unroll
    for (int q=0;q<4;q++) {
      float4 av = Ap[q];
      A2[4*q+0]=-__expf(av.x)*LOG2E; A2[4*q+1]=-__expf(av.y)*LOG2E;
      A2[4*q+2]=-__expf(av.z)*LOG2E; A2[4*q+3]=-__expf(av.w)*LOG2E;
    }
  }
  __syncthreads();
  // phase 1: all dt/du (trans-heavy, independent of h)
  float dtv[SEGLEN], duv[SEGLEN];
  float sdt = 0.f;
  #pragma unroll
  for (int j=0;j<SEGLEN;j++) {
    const float* row = &rows[sub][j][0];
    float4 d0 = *((const float4*)row);
    float2 d1 = *((const float2*)(row+4));
    float raw = bias + w[0]*d0.x + w[1]*d0.y + w[2]*d0.z + w[3]*d0.w
              + w[4]*d1.x + w[5]*d1.y;
    float dt = softplus_f(raw);
    dtv[j] = dt;
    duv[j] = dt * uld[sub][j][c];
    sdt += dt;
  }
  // phase 2: h recurrence (exp2+FMA only; dt known ahead)
  float h[16];
  #pragma unroll
  for (int n=0;n<16;n++) h[n]=0.f;
  #pragma unroll
  for (int j=0;j<SEGLEN;j++) {
    float dt = dtv[j], du = duv[j];
    const float4* Bv = (const float4*)(&rows[sub][j][8]);
    #pragma unroll
    for (int q=0;q<4;q++) {
      float4 bv = Bv[q];
      h[4*q+0] = h[4*q+0]*__builtin_amdgcn_exp2f(dt*A2[4*q+0]) + du*bv.x;
      h[4*q+1] = h[4*q+1]*__builtin_amdgcn_exp2f(dt*A2[4*q+1]) + du*bv.y;
      h[4*q+2] = h[4*q+2]*__builtin_amdgcn_exp2f(dt*A2[4*q+2]) + du*bv.z;
      h[4*q+3] = h[4*q+3]*__builtin_amdgcn_exp2f(dt*A2[4*q+3]) + du*bv.w;
    }
  }
  float* ho = hend + ((size_t)s*8 + bk)*(DI*Ns) + c;
  #pragma unroll
  for (int n=0;n<16;n++) ho[(size_t)n*DI] = h[n];
  sdt_o[((size_t)s*8 + bk)*DI + c] = sdt;
}

// fix-up: hend -> h_init in place; 64-thread blocks so all 256 CUs participate
__global__ __launch_bounds__(64) void k_fix(float* __restrict__ hend,
    const float* __restrict__ sdt, const float* __restrict__ A_log) {
  int t = blockIdx.x*64 + threadIdx.x;
  int c = t % DI;
  int nn = (t / DI) & 15;
  int bk = t / (DI*Ns);
  int k = bk & 3;
  float A = -__expf(A_log[((size_t)k*DI + c)*Ns + nn]);
  float hi = 0.f;
  #pragma unroll 8
  for (int s=0; s<SEG; s++) {
    float he = hend[(size_t)s*NBKCN + t];
    float P  = __expf(A * sdt[(size_t)s*(8*DI) + bk*DI + c]);
    hend[(size_t)s*NBKCN + t] = hi;
    hi = he + P*hi;
  }
}

// pass B: rescan from h_init; f4 staging; dt/du precomputed; y scattered to original p
__global__ __launch_bounds__(384) void k_scanB(const float* __restrict__ v_t,
    const float* __restrict__ dblp, const float* __restrict__ dtw,
    const float* __restrict__ dtb, const float* __restrict__ A_log,
    const float* __restrict__ hinit, float* __restrict__ ym) {
  __shared__ float uld[2][SEGLEN][DI];
  __shared__ float rows[2][SEGLEN][RW];
  int t = threadIdx.x;
  int sub = t/192, tl = t - sub*192;
  int s = blockIdx.x*2 + sub;
  int k = blockIdx.y, b = blockIdx.z;
  int bk = b*4 + k;
  int pbase, pstr; dir_map(k, s, pbase, pstr);
  #pragma unroll
  for (int i=0;i<4;i++) {
    int idx = tl + i*192;
    int row = idx/48, q = idx - row*48;
    int p = pbase + row*pstr;
    const float4* src = (const float4*)(v_t + ((size_t)b*LL + p)*DI) + q;
    *((float4*)&uld[sub][row][4*q]) = *src;
  }
  if (tl < 160) {
    int r = tl/10, q = tl - r*10;
    const float4* src = (const float4*)(dblp + ((size_t)bk*LL + pbase + r*pstr)*RW);
    *((float4*)&rows[sub][r][4*q]) = src[q];
  }
  int c = tl;
  float w[6];
  {
    const float* wr = dtw + ((size_t)k*DI + c)*Rr;
    #pragma unroll
    for (int r=0;r<6;r++) w[r] = wr[r];
  }
  float bias = dtb[k*DI + c];
  float A2[16];
  {
    const float4* Ap = (const float4*)(A_log + ((size_t)k*DI + c)*Ns);
    #pragma unroll
    for (int q=0;q<4;q++) {
      float4 av = Ap[q];
      A2[4*q+0]=-__expf(av.x)*LOG2E; A2[4*q+1]=-__expf(av.y)*LOG2E;
      A2[4*q+2]=-__expf(av.z)*LOG2E; A2[4*q+3]=-__expf(av.w)*LOG2E;
    }
  }
  float h[16];
  {
    const float* hi = hinit + ((size_t)s*8 + bk)*(DI*Ns) + c;
    #pragma unroll
    for (int n=0;n<16;n++) h[n] = hi[(size_t)n*DI];
  }
  __syncthreads();
  // phase 1: dt/du precompute
  float dtv[SEGLEN], duv[SEGLEN];
  #pragma unroll
  for (int j=0;j<SEGLEN;j++) {
    const float* row = &rows[sub][j][0];
    float4 d0 = *((const float4*)row);
    float2 d1 = *((const float2*)(row+4));
    float raw = bias + w[0]*d0.x + w[1]*d0.y + w[2]*d0.z + w[3]*d0.w
              + w[4]*d1.x + w[5]*d1.y;
    float dt = softplus_f(raw);
    dtv[j] = dt;
    duv[j] = dt * uld[sub][j][c];
  }
  // phase 2: h recurrence + y
  float* ymk = ym + ((size_t)(k*Bb + b)*LL)*DI;
  #pragma unroll
  for (int j=0;j<SEGLEN;j++) {
    float dt = dtv[j], du = duv[j];
    const float4* Bv = (const float4*)(&rows[sub][j][8]);
    const float4* Cv = (const float4*)(&rows[sub][j][24]);
    float y = 0.f;
    #pragma unroll
    for (int q=0;q<4;q++) {
      float4 bv = Bv[q];
      float4 cv = Cv[q];
      h[4*q+0] = h[4*q+0]*__builtin_amdgcn_exp2f(dt*A2[4*q+0]) + du*bv.x;
      h[4*q+1] = h[4*q+1]*__builtin_amdgcn_exp2f(dt*A2[4*q+1]) + du*bv.y;
      h[4*q+2] = h[4*q+2]*__builtin_amdgcn_exp2f(dt*A2[4*q+2]) + du*bv.z;
      h[4*q+3] = h[4*q+3]*__builtin_amdgcn_exp2f(dt*A2[4*q+3]) + du*bv.w;
      y += h[4*q+0]*cv.x + h[4*q+1]*cv.y + h[4*q+2]*cv.z + h[4*q+3]*cv.w;
    }
    int p = pbase + j*pstr;
    ymk[(size_t)p*DI + c] = y;
  }
}

// fused: merge 4 dirs + D + chanLN(192) + out_proj + skip -> out
__global__ __launch_bounds__(384) void k_merge_out(const float* __restrict__ ym,
    const float* __restrict__ v_t, const float* __restrict__ Ds,
    const float* __restrict__ g, const float* __restrict__ be,
    const float* __restrict__ w3, const float* __restrict__ x1,
    const float* __restrict__ ss, float* __restrict__ out) {
  __shared__ float tile2[16*196];
  __shared__ float red[2][16][6];
  int t = threadIdx.x;
  int b = blockIdx.y;
  int l0 = blockIdx.x*16;
  int pp = t / 192, c = t - pp*192;
  int wv = t >> 6;
  int ln = t & 63;
  float sd = Ds[c] + Ds[DI+c] + Ds[2*DI+c] + Ds[3*DI+c];
  float gg = g[c], bb = be[c];
  float v[8];
  #pragma unroll
  for (int j=0;j<8;j++) {
    int i = 2*j + pp;
    size_t row = ((size_t)b*LL + l0 + i)*DI + c;
    float vv = ym[row] + ym[(size_t)2*LL*DI + row]
             + ym[(size_t)4*LL*DI + row] + ym[(size_t)6*LL*DI + row]
             + v_t[row]*sd;
    v[j] = vv;
    float s = vv, s2 = vv*vv;
    #pragma unroll
    for (int d=1; d<64; d<<=1) { s += __shfl_xor(s,d); s2 += __shfl_xor(s2,d); }
    if (ln==0) { red[0][i][wv]=s; red[1][i][wv]=s2; }
  }
  __syncthreads();
  #pragma unroll
  for (int j=0;j<8;j++) {
    int i = 2*j + pp;
    int w0i = pp*3;
    float S  = red[0][i][w0i]+red[0][i][w0i+1]+red[0][i][w0i+2];
    float S2 = red[1][i][w0i]+red[1][i][w0i+1]+red[1][i][w0i+2];
    float mu = S*(1.f/DI);
    float var = S2*(1.f/DI) - mu*mu;
    float r = rsqrtf(var + LNEPS);
    tile2[i*196 + c] = (v[j]-mu)*r*gg + bb;
  }
  __syncthreads();
  int l = t & 15, og = t >> 4;
  float a0=0.f,a1=0.f,a2=0.f,a3=0.f;
  {
    const float4* yr = (const float4*)&tile2[l*196];
    const float4* wr0 = (const float4*)(w3 + (size_t)(og*4+0)*DI);
    const float4* wr1 = (const float4*)(w3 + (size_t)(og*4+1)*DI);
    const float4* wr2 = (const float4*)(w3 + (size_t)(og*4+2)*DI);
    const float4* wr3 = (const float4*)(w3 + (size_t)(og*4+3)*DI);
    #pragma unroll 6
    for (int j=0;j<48;j++) {
      float4 yv = yr[j];
      float4 v0 = wr0[j], v1 = wr1[j], v2 = wr2[j], v3 = wr3[j];
      a0 += yv.x*v0.x + yv.y*v0.y + yv.z*v0.z + yv.w*v0.w;
      a1 += yv.x*v1.x + yv.y*v1.y + yv.z*v1.z + yv.w*v1.w;
      a2 += yv.x*v2.x + yv.y*v2.y + yv.z*v2.z + yv.w*v2.w;
      a3 += yv.x*v3.x + yv.y*v3.y + yv.z*v3.z + yv.w*v3.w;
    }
  }
  float sc = ss[0];
  int o0 = og*4;
  size_t ob = ((size_t)b*HD + o0)*LL + l0 + l;
  out[ob]            = a0 + x1[ob]*sc;
  out[ob+LL]         = a1 + x1[ob+LL]*sc;
  out[ob+2*(size_t)LL] = a2 + x1[ob+2*(size_t)LL]*sc;
  out[ob+3*(size_t)LL] = a3 + x1[ob+3*(size_t)LL]*sc;
}

extern "C" void kernel_launch(void* const* d_in, const int* in_sizes, int n_in,
                              void* d_out, int out_size, void* d_ws, size_t ws_size,
                              hipStream_t stream) {
  const float* x         = (const float*)d_in[0];
  const float* in_conv_w = (const float*)d_in[1];
  const float* ln1_g     = (const float*)d_in[2];
  const float* ln1_b     = (const float*)d_in[3];
  const float* in_proj_w = (const float*)d_in[4];
  const float* dw_w      = (const float*)d_in[5];
  const float* dw_b      = (const float*)d_in[6];
  const float* x_proj_w  = (const float*)d_in[7];
  const float* dt_proj_w = (const float*)d_in[8];
  const float* dt_proj_b = (const float*)d_in[9];
  const float* A_log     = (const float*)d_in[10];
  const float* Ds        = (const float*)d_in[11];
  const float* onorm_g   = (const float*)d_in[12];
  const float* onorm_b   = (const float*)d_in[13];
  const float* out_proj_w= (const float*)d_in[14];
  const float* skip_s    = (const float*)d_in[15];
  float* out = (float*)d_out;

  float* ws   = (float*)d_ws;
  float* x1   = ws;                  //   786,432
  float* hp   = x1   + 786432;       // 1,572,864
  float* v_t  = hp   + 1572864;      // 1,572,864
  float* dblp = v_t  + 1572864;      // 1,310,720
  float* hend = dblp + 1310720;      // 6,291,456
  float* sdt  = hend + 6291456;      //   393,216
  float* ym   = sdt  + 393216;       // 6,291,456 (4 x [b][p][c])

  k_fused_in<<<dim3(LL/16, Bb), dim3(384), 0, stream>>>(x, in_conv_w, ln1_g, ln1_b, in_proj_w, x1, hp);
  k_dwconv_silu_t<<<dim3(64, 8, Bb), dim3(192), 0, stream>>>(hp, dw_w, dw_b, v_t);
  k_proj   <<<dim3(LL/64, Kd, Bb), dim3(512), 0, stream>>>(v_t, x_proj_w, dblp);
  k_scanA  <<<dim3(SEG/2, Kd, Bb), dim3(384), 0, stream>>>(v_t, dblp, dt_proj_w, dt_proj_b, A_log, hend, sdt);
  k_fix    <<<dim3(NBKCN/64), dim3(64), 0, stream>>>(hend, sdt, A_log);
  k_scanB  <<<dim3(SEG/2, Kd, Bb), dim3(384), 0, stream>>>(v_t, dblp, dt_proj_w, dt_proj_b, A_log, hend, ym);
  k_merge_out<<<dim3(LL/16, Bb), dim3(384), 0, stream>>>(ym, v_t, Ds, onorm_g, onorm_b, out_proj_w, x1, skip_s, out);
}